// Round 2
// baseline (428.171 us; speedup 1.0000x reference)
//
#include <hip/hip_runtime.h>
#include <math.h>

#define N_DIA 48
#define DLEN  64
#define NTOT  3072     // N utterances
#define DD    512      // D == H
#define M3    9216     // 3N

#define SCALE_F 0.99999f
#define PI_F    3.14159274101257324f

__device__ __forceinline__ float ang_sim(float cs) {
    float cc = cs * SCALE_F;
    cc = fminf(fmaxf(cc, -SCALE_F), SCALE_F);
    return 1.0f - acosf(cc) / PI_F;
}

// ---------- K1: xl = l + W_spk[argmax(qmask)] ----------
__global__ void k_xl(const float* __restrict__ l, const float* __restrict__ qmask,
                     const float* __restrict__ Wspk, float* __restrict__ xl) {
    int i = blockIdx.x;               // utterance row
    int pos = i & 63, dia = i >> 6;
    int qb = (pos * N_DIA + dia) * 2;
    float q0 = qmask[qb], q1 = qmask[qb + 1];
    int spk = (q0 >= q1) ? 0 : 1;     // argmax, first-on-tie
    const float4* lv = (const float4*)(l + (size_t)i * DD);
    const float4* wv = (const float4*)(Wspk + (size_t)spk * DD);
    float4* ov = (float4*)(xl + (size_t)i * DD);
    int t = threadIdx.x;              // 128 threads, 128 float4 = 512 floats
    float4 a = lv[t], b = wv[t];
    ov[t] = make_float4(a.x + b.x, a.y + b.y, a.z + b.z, a.w + b.w);
}

// ---------- K2: inverse L2 norms of all 9216 rows ----------
__global__ void k_invnorm(const float* __restrict__ a, const float* __restrict__ v,
                          const float* __restrict__ xl, float* __restrict__ invn) {
    int r = blockIdx.x;               // 0..9215
    int m = r / NTOT, i = r % NTOT;
    const float* src = (m == 0) ? a : (m == 1) ? v : xl;
    const float4* p = (const float4*)(src + (size_t)i * DD);
    int lane = threadIdx.x;           // 64
    float s = 0.f;
#pragma unroll
    for (int e = 0; e < 2; e++) {
        float4 x = p[lane * 2 + e];
        s += x.x * x.x + x.y * x.y + x.z * x.z + x.w * x.w;
    }
#pragma unroll
    for (int off = 32; off; off >>= 1) s += __shfl_down(s, off, 64);
    if (lane == 0) invn[r] = 1.0f / sqrtf(s);
}

// ---------- K3: per-dialogue 64x64 angular-sim Gram blocks ----------
__global__ __launch_bounds__(256) void k_gram(const float* __restrict__ a,
                                              const float* __restrict__ v,
                                              const float* __restrict__ xl,
                                              const float* __restrict__ invn,
                                              float* __restrict__ blk) {
    __shared__ float tile[64][132];   // 64 rows x 128 K-chunk, padded
    int d = blockIdx.x, m = blockIdx.y;
    const float* src = (m == 0) ? a : (m == 1) ? v : xl;
    int dbase = d * 64;
    int t = threadIdx.x;
    int tx = t & 15, ty = t >> 4;
    float acc[4][4] = {};
    for (int kt = 0; kt < 4; ++kt) {
        __syncthreads();
#pragma unroll
        for (int q = 0; q < 8; ++q) {
            int f4 = t + 256 * q;            // 0..2047
            int row = f4 >> 5, c4 = f4 & 31;
            float sc = invn[m * NTOT + dbase + row];
            float4 x = *(const float4*)(src + (size_t)(dbase + row) * DD + kt * 128 + c4 * 4);
            float4 y = make_float4(x.x * sc, x.y * sc, x.z * sc, x.w * sc);
            *(float4*)&tile[row][c4 * 4] = y;
        }
        __syncthreads();
#pragma unroll
        for (int kk = 0; kk < 32; ++kk) {
            float4 ar[4], br[4];
#pragma unroll
            for (int u = 0; u < 4; u++) {
                ar[u] = *(const float4*)&tile[ty * 4 + u][kk * 4];
                br[u] = *(const float4*)&tile[tx * 4 + u][kk * 4];
            }
#pragma unroll
            for (int ii = 0; ii < 4; ii++)
#pragma unroll
                for (int jj = 0; jj < 4; jj++)
                    acc[ii][jj] += ar[ii].x * br[jj].x + ar[ii].y * br[jj].y +
                                   ar[ii].z * br[jj].z + ar[ii].w * br[jj].w;
        }
    }
    size_t base = (size_t)(m * N_DIA + d) * 4096;
#pragma unroll
    for (int ii = 0; ii < 4; ii++)
#pragma unroll
        for (int jj = 0; jj < 4; jj++)
            blk[base + (size_t)(ty * 4 + ii) * 64 + tx * 4 + jj] = ang_sim(acc[ii][jj]);
}

// ---------- K4: cross-modality diagonal sims ----------
__global__ void k_cross(const float* __restrict__ a, const float* __restrict__ v,
                        const float* __restrict__ xl, const float* __restrict__ invn,
                        float* __restrict__ cross) {
    int r = blockIdx.x;               // p*NTOT + i, p: 0=(a,v) 1=(a,l) 2=(v,l)
    int p = r / NTOT, i = r % NTOT;
    const float *s1, *s2; int m1, m2;
    if (p == 0)      { s1 = a; s2 = v;  m1 = 0; m2 = 1; }
    else if (p == 1) { s1 = a; s2 = xl; m1 = 0; m2 = 2; }
    else             { s1 = v; s2 = xl; m1 = 1; m2 = 2; }
    int lane = threadIdx.x;
    const float4* p1 = (const float4*)(s1 + (size_t)i * DD);
    const float4* p2 = (const float4*)(s2 + (size_t)i * DD);
    float s = 0.f;
#pragma unroll
    for (int e = 0; e < 2; e++) {
        float4 x = p1[lane * 2 + e], y = p2[lane * 2 + e];
        s += x.x * y.x + x.y * y.y + x.z * y.z + x.w * y.w;
    }
#pragma unroll
    for (int off = 32; off; off >>= 1) s += __shfl_down(s, off, 64);
    if (lane == 0) {
        float cs = s * invn[m1 * NTOT + i] * invn[m2 * NTOT + i];
        cross[r] = ang_sim(cs);
    }
}

// ---------- K5: row sums -> dinv = rsqrt(degree) ----------
__global__ void k_dinv(const float* __restrict__ blk, const float* __restrict__ cross,
                       float* __restrict__ dinv) {
    int r = blockIdx.x;               // 0..9215
    int m = r / NTOT, i = r % NTOT;
    int d = i >> 6, ir = i & 63;
    int lane = threadIdx.x;
    float s = blk[((size_t)(m * N_DIA + d) * 64 + ir) * 64 + lane];
#pragma unroll
    for (int off = 32; off; off >>= 1) s += __shfl_down(s, off, 64);
    if (lane == 0) {
        float c1, c2;
        if (m == 0)      { c1 = cross[0 * NTOT + i]; c2 = cross[1 * NTOT + i]; }
        else if (m == 1) { c1 = cross[0 * NTOT + i]; c2 = cross[2 * NTOT + i]; }
        else             { c1 = cross[1 * NTOT + i]; c2 = cross[2 * NTOT + i]; }
        dinv[r] = 1.0f / sqrtf(s + c1 + c2);
    }
}

// ---------- K6: fp32 GEMM [9216x512] @ [512x512], fused epilogues ----------
// mode 0: out = relu(acc + bias[col])
// mode 1: out = relu(theta*acc + (1-theta)*resid[row,col])
__global__ __launch_bounds__(256) void k_gemm(
    const float* __restrict__ A0, const float* __restrict__ A1, const float* __restrict__ A2,
    const float* __restrict__ W, const float* __restrict__ bias,
    const float* __restrict__ resid, float* __restrict__ out, float theta, int mode) {
    __shared__ float As[16][132];     // [k][m] transposed
    __shared__ float Bs[16][68];      // [k][n]
    int nbase = blockIdx.x * 64;
    int mbase = blockIdx.y * 128;
    int mm = mbase / NTOT;
    int lrow = mbase % NTOT;          // 128-row tiles never cross modality (3072 % 128 == 0)
    const float* A = (mm == 0) ? A0 : (mm == 1) ? A1 : A2;
    int t = threadIdx.x, tx = t & 15, ty = t >> 4;
    float4 acc[8];
#pragma unroll
    for (int i = 0; i < 8; i++) acc[i] = make_float4(0.f, 0.f, 0.f, 0.f);

    for (int kt = 0; kt < DD; kt += 16) {
        __syncthreads();
#pragma unroll
        for (int q = 0; q < 2; q++) {
            int f4 = t * 2 + q;            // 0..511 over 128 rows x 4 float4
            int row = f4 >> 2, c4 = f4 & 3;
            float4 x = *(const float4*)(A + (size_t)(lrow + row) * DD + kt + c4 * 4);
            As[c4 * 4 + 0][row] = x.x; As[c4 * 4 + 1][row] = x.y;
            As[c4 * 4 + 2][row] = x.z; As[c4 * 4 + 3][row] = x.w;
        }
        {
            int k = t >> 4, c4 = t & 15;
            float4 w = *(const float4*)(W + (size_t)(kt + k) * DD + nbase + c4 * 4);
            *(float4*)&Bs[k][c4 * 4] = w;
        }
        __syncthreads();
#pragma unroll
        for (int k = 0; k < 16; k++) {
            float4 a0 = *(const float4*)&As[k][ty * 8];
            float4 a1 = *(const float4*)&As[k][ty * 8 + 4];
            float4 b  = *(const float4*)&Bs[k][tx * 4];
            float av[8] = {a0.x, a0.y, a0.z, a0.w, a1.x, a1.y, a1.z, a1.w};
#pragma unroll
            for (int i = 0; i < 8; i++) {
                acc[i].x += av[i] * b.x; acc[i].y += av[i] * b.y;
                acc[i].z += av[i] * b.z; acc[i].w += av[i] * b.w;
            }
        }
    }
#pragma unroll
    for (int i = 0; i < 8; i++) {
        int grow = mbase + ty * 8 + i;
        int gcol = nbase + tx * 4;
        float4 r = acc[i];
        if (mode == 0) {
            r.x += bias[gcol]; r.y += bias[gcol + 1];
            r.z += bias[gcol + 2]; r.w += bias[gcol + 3];
        } else {
            float4 sv = *(const float4*)(resid + (size_t)grow * DD + gcol);
            float om = 1.0f - theta;
            r.x = theta * r.x + om * sv.x; r.y = theta * r.y + om * sv.y;
            r.z = theta * r.z + om * sv.z; r.w = theta * r.w + om * sv.w;
        }
        r.x = fmaxf(r.x, 0.f); r.y = fmaxf(r.y, 0.f);
        r.z = fmaxf(r.z, 0.f); r.w = fmaxf(r.w, 0.f);
        *(float4*)(out + (size_t)grow * DD + gcol) = r;
    }
}

// ---------- K7: sparse adj @ h -> support = 0.9*hi + 0.1*h0 ----------
__global__ __launch_bounds__(256) void k_adjmul(
    const float* __restrict__ blk, const float* __restrict__ cross,
    const float* __restrict__ dinv, const float* __restrict__ h,
    const float* __restrict__ h0, float* __restrict__ sup) {
    __shared__ float Ab[64][64];
    __shared__ float4 hs[64][32];
    int cc = blockIdx.x;              // column chunk (128 floats each)
    int d = blockIdx.y, m = blockIdx.z;
    int dbase = d * 64, cb = cc * 128;
    int t = threadIdx.x;
    size_t bbase = (size_t)(m * N_DIA + d) * 4096;
#pragma unroll
    for (int q = 0; q < 16; q++) {
        int e = t + 256 * q;
        int i = e >> 6, j = e & 63;
        Ab[i][j] = blk[bbase + e] * dinv[m * NTOT + dbase + i] * dinv[m * NTOT + dbase + j];
    }
#pragma unroll
    for (int q = 0; q < 8; q++) {
        int f4 = t + 256 * q;
        int j = f4 >> 5, c4 = f4 & 31;
        hs[j][c4] = *(const float4*)(h + (size_t)(m * NTOT + dbase + j) * DD + cb + c4 * 4);
    }
    __syncthreads();
    int tx = t & 31, ty = t >> 5;     // tx: float4 col, ty: 8 row groups
    float4 acc[8];
#pragma unroll
    for (int i = 0; i < 8; i++) acc[i] = make_float4(0.f, 0.f, 0.f, 0.f);
    for (int j = 0; j < 64; j++) {
        float4 b = hs[j][tx];
#pragma unroll
        for (int rr = 0; rr < 8; rr++) {
            float aw = Ab[ty * 8 + rr][j];
            acc[rr].x += aw * b.x; acc[rr].y += aw * b.y;
            acc[rr].z += aw * b.z; acc[rr].w += aw * b.w;
        }
    }
#pragma unroll
    for (int rr = 0; rr < 8; rr++) {
        int i = ty * 8 + rr;
        int gi = dbase + i;
        float dm = dinv[m * NTOT + gi];
#pragma unroll
        for (int n = 0; n < 3; n++) {
            if (n == m) continue;
            int p = m + n - 1;        // (0,1)->0 (0,2)->1 (1,2)->2
            float cval = cross[p * NTOT + gi] * dm * dinv[n * NTOT + gi];
            float4 hv = *(const float4*)(h + (size_t)(n * NTOT + gi) * DD + cb + tx * 4);
            acc[rr].x += cval * hv.x; acc[rr].y += cval * hv.y;
            acc[rr].z += cval * hv.z; acc[rr].w += cval * hv.w;
        }
        size_t o = (size_t)(m * NTOT + gi) * DD + cb + tx * 4;
        float4 h0v = *(const float4*)(h0 + o);
        float4 r = make_float4(0.9f * acc[rr].x + 0.1f * h0v.x,
                               0.9f * acc[rr].y + 0.1f * h0v.y,
                               0.9f * acc[rr].z + 0.1f * h0v.z,
                               0.9f * acc[rr].w + 0.1f * h0v.w);
        *(float4*)(sup + o) = r;
    }
}

// ---------- K8: assemble output [3072 x 3072] ----------
__global__ void k_out(const float* __restrict__ a, const float* __restrict__ v,
                      const float* __restrict__ xl, const float* __restrict__ h,
                      float* __restrict__ out) {
    int i = blockIdx.x, t = threadIdx.x;
#pragma unroll
    for (int q = 0; q < 3; q++) {
        int f4 = t + 256 * q;              // 0..767
        int c = f4 * 4;                    // 0..3068
        int m = c >> 10;                   // / 1024
        int ccol = c & 1023;
        float4 val;
        if (ccol < 512) {
            const float* src = (m == 0) ? a : (m == 1) ? v : xl;
            val = *(const float4*)(src + (size_t)i * DD + ccol);
        } else {
            val = *(const float4*)(h + (size_t)(m * NTOT + i) * DD + (ccol - 512));
        }
        *(float4*)(out + (size_t)i * 3072 + c) = val;
    }
}

extern "C" void kernel_launch(void* const* d_in, const int* in_sizes, int n_in,
                              void* d_out, int out_size, void* d_ws, size_t ws_size,
                              hipStream_t stream) {
    (void)in_sizes; (void)n_in; (void)out_size;
    const float* a     = (const float*)d_in[0];
    const float* v     = (const float*)d_in[1];
    const float* l     = (const float*)d_in[2];
    const float* qmask = (const float*)d_in[3];
    // d_in[4] = dia_len (static, all 64) — unused
    const float* Wspk  = (const float*)d_in[5];
    const float* W0    = (const float*)d_in[6];
    const float* b0    = (const float*)d_in[7];
    const float* Wg    = (const float*)d_in[8];
    float* out = (float*)d_out;
    float* ws = (float*)d_ws;

    const size_t big = (size_t)M3 * DD;             // 4,718,592 floats
    float* xl    = ws;                              // 1,572,864
    float* invn  = xl + (size_t)NTOT * DD;          // 9,216
    float* blk   = invn + 3 * NTOT;                 // 589,824
    float* cross = blk + (size_t)3 * N_DIA * 4096;  // 9,216
    float* dinvp = cross + 3 * NTOT;                // 9,216
    float* base  = dinvp + 3 * NTOT;
    size_t small = (size_t)(base - ws);
    float *h0, *h, *sup;
    if (ws_size >= (small + 3 * big) * sizeof(float)) {
        h0 = base; h = base + big; sup = base + 2 * big;
    } else {
        // fall back: park h0 in d_out (out_size 9.4M floats >= 4.7M; fully
        // rewritten by k_out at the end, after last h0 use)
        h0 = out; h = base; sup = base + big;
    }

    k_xl     <<<NTOT, 128, 0, stream>>>(l, qmask, Wspk, xl);
    k_invnorm<<<M3, 64, 0, stream>>>(a, v, xl, invn);
    k_gram   <<<dim3(N_DIA, 3), 256, 0, stream>>>(a, v, xl, invn, blk);
    k_cross  <<<M3, 64, 0, stream>>>(a, v, xl, invn, cross);
    k_dinv   <<<M3, 64, 0, stream>>>(blk, cross, dinvp);

    // h0 = relu(x @ W0 + b0)
    k_gemm<<<dim3(8, 72), 256, 0, stream>>>(a, v, xl, W0, b0, nullptr, h0, 0.f, 0);

    const float th1 = 0.40546510810816438f;  // log(1.5)
    const float th2 = 0.22314355131420976f;  // log(1.25)

    // layer 1 (h_in = h0)
    k_adjmul<<<dim3(4, N_DIA, 3), 256, 0, stream>>>(blk, cross, dinvp, h0, h0, sup);
    k_gemm<<<dim3(8, 72), 256, 0, stream>>>(sup, sup + (size_t)NTOT * DD, sup + (size_t)2 * NTOT * DD,
                                            Wg, nullptr, sup, h, th1, 1);
    // layer 2
    k_adjmul<<<dim3(4, N_DIA, 3), 256, 0, stream>>>(blk, cross, dinvp, h, h0, sup);
    k_gemm<<<dim3(8, 72), 256, 0, stream>>>(sup, sup + (size_t)NTOT * DD, sup + (size_t)2 * NTOT * DD,
                                            Wg + (size_t)DD * DD, nullptr, sup, h, th2, 1);

    k_out<<<NTOT, 256, 0, stream>>>(a, v, xl, h, out);
}

// Round 3
// 280.556 us; speedup vs baseline: 1.5262x; 1.5262x over previous
//
#include <hip/hip_runtime.h>
#include <math.h>

#define N_DIA 48
#define NTOT  3072     // N utterances
#define DD    512      // D == H
#define M3    9216     // 3N
#define SEG   ((size_t)NTOT * DD)

#define SCALE_F 0.99999f
#define PI_F    3.14159274101257324f

typedef __attribute__((ext_vector_type(8))) short frag8;
typedef __attribute__((ext_vector_type(4))) float f32x4;

__device__ __forceinline__ float ang_sim(float cs) {
    float cc = cs * SCALE_F;
    cc = fminf(fmaxf(cc, -SCALE_F), SCALE_F);
    return 1.0f - acosf(cc) / PI_F;
}
__device__ __forceinline__ unsigned short f2bf(float x) {
    union { float f; unsigned int u; } c; c.f = x;
    unsigned int r = c.u + 0x7fffu + ((c.u >> 16) & 1u);
    return (unsigned short)(r >> 16);
}
__device__ __forceinline__ float bf2f(unsigned short h) {
    union { unsigned int u; float f; } c; c.u = ((unsigned int)h) << 16;
    return c.f;
}
__device__ __forceinline__ void gload16(const unsigned short* g, unsigned short* s) {
    __builtin_amdgcn_global_load_lds(
        (const __attribute__((address_space(1))) unsigned int*)g,
        (__attribute__((address_space(3))) unsigned int*)s, 16, 0, 0);
}

// ---------- K1: xl = l + W_spk[argmax(qmask)] ----------
__global__ void k_xl(const float* __restrict__ l, const float* __restrict__ qmask,
                     const float* __restrict__ Wspk, float* __restrict__ xl) {
    int i = blockIdx.x;
    int pos = i & 63, dia = i >> 6;
    int qb = (pos * N_DIA + dia) * 2;
    float q0 = qmask[qb], q1 = qmask[qb + 1];
    int spk = (q0 >= q1) ? 0 : 1;
    const float4* lv = (const float4*)(l + (size_t)i * DD);
    const float4* wv = (const float4*)(Wspk + (size_t)spk * DD);
    float4* ov = (float4*)(xl + (size_t)i * DD);
    int t = threadIdx.x;
    float4 a = lv[t], b = wv[t];
    ov[t] = make_float4(a.x + b.x, a.y + b.y, a.z + b.z, a.w + b.w);
}

// ---------- K2: inverse L2 norms ----------
__global__ void k_invnorm(const float* __restrict__ a, const float* __restrict__ v,
                          const float* __restrict__ xl, float* __restrict__ invn) {
    int r = blockIdx.x;
    int m = r / NTOT, i = r % NTOT;
    const float* src = (m == 0) ? a : (m == 1) ? v : xl;
    const float4* p = (const float4*)(src + (size_t)i * DD);
    int lane = threadIdx.x;
    float s = 0.f;
#pragma unroll
    for (int e = 0; e < 2; e++) {
        float4 x = p[lane * 2 + e];
        s += x.x * x.x + x.y * x.y + x.z * x.z + x.w * x.w;
    }
#pragma unroll
    for (int off = 32; off; off >>= 1) s += __shfl_down(s, off, 64);
    if (lane == 0) invn[r] = 1.0f / sqrtf(s);
}

// ---------- K3: per-dialogue 64x64 angular-sim Gram blocks ----------
__global__ __launch_bounds__(256) void k_gram(const float* __restrict__ a,
                                              const float* __restrict__ v,
                                              const float* __restrict__ xl,
                                              const float* __restrict__ invn,
                                              float* __restrict__ blk) {
    __shared__ float tile[64][132];
    int d = blockIdx.x, m = blockIdx.y;
    const float* src = (m == 0) ? a : (m == 1) ? v : xl;
    int dbase = d * 64;
    int t = threadIdx.x;
    int tx = t & 15, ty = t >> 4;
    float acc[4][4] = {};
    for (int kt = 0; kt < 4; ++kt) {
        __syncthreads();
#pragma unroll
        for (int q = 0; q < 8; ++q) {
            int f4 = t + 256 * q;
            int row = f4 >> 5, c4 = f4 & 31;
            float sc = invn[m * NTOT + dbase + row];
            float4 x = *(const float4*)(src + (size_t)(dbase + row) * DD + kt * 128 + c4 * 4);
            float4 y = make_float4(x.x * sc, x.y * sc, x.z * sc, x.w * sc);
            *(float4*)&tile[row][c4 * 4] = y;
        }
        __syncthreads();
#pragma unroll
        for (int kk = 0; kk < 32; ++kk) {
            float4 ar[4], br[4];
#pragma unroll
            for (int u = 0; u < 4; u++) {
                ar[u] = *(const float4*)&tile[ty * 4 + u][kk * 4];
                br[u] = *(const float4*)&tile[tx * 4 + u][kk * 4];
            }
#pragma unroll
            for (int ii = 0; ii < 4; ii++)
#pragma unroll
                for (int jj = 0; jj < 4; jj++)
                    acc[ii][jj] += ar[ii].x * br[jj].x + ar[ii].y * br[jj].y +
                                   ar[ii].z * br[jj].z + ar[ii].w * br[jj].w;
        }
    }
    size_t base = (size_t)(m * N_DIA + d) * 4096;
#pragma unroll
    for (int ii = 0; ii < 4; ii++)
#pragma unroll
        for (int jj = 0; jj < 4; jj++)
            blk[base + (size_t)(ty * 4 + ii) * 64 + tx * 4 + jj] = ang_sim(acc[ii][jj]);
}

// ---------- K4: cross-modality diagonal sims ----------
__global__ void k_cross(const float* __restrict__ a, const float* __restrict__ v,
                        const float* __restrict__ xl, const float* __restrict__ invn,
                        float* __restrict__ cross) {
    int r = blockIdx.x;
    int p = r / NTOT, i = r % NTOT;
    const float *s1, *s2; int m1, m2;
    if (p == 0)      { s1 = a; s2 = v;  m1 = 0; m2 = 1; }
    else if (p == 1) { s1 = a; s2 = xl; m1 = 0; m2 = 2; }
    else             { s1 = v; s2 = xl; m1 = 1; m2 = 2; }
    int lane = threadIdx.x;
    const float4* p1 = (const float4*)(s1 + (size_t)i * DD);
    const float4* p2 = (const float4*)(s2 + (size_t)i * DD);
    float s = 0.f;
#pragma unroll
    for (int e = 0; e < 2; e++) {
        float4 x = p1[lane * 2 + e], y = p2[lane * 2 + e];
        s += x.x * y.x + x.y * y.y + x.z * y.z + x.w * y.w;
    }
#pragma unroll
    for (int off = 32; off; off >>= 1) s += __shfl_down(s, off, 64);
    if (lane == 0) {
        float cs = s * invn[m1 * NTOT + i] * invn[m2 * NTOT + i];
        cross[r] = ang_sim(cs);
    }
}

// ---------- K5: degree -> dinv ----------
__global__ void k_dinv(const float* __restrict__ blk, const float* __restrict__ cross,
                       float* __restrict__ dinv) {
    int r = blockIdx.x;
    int m = r / NTOT, i = r % NTOT;
    int d = i >> 6, ir = i & 63;
    int lane = threadIdx.x;
    float s = blk[((size_t)(m * N_DIA + d) * 64 + ir) * 64 + lane];
#pragma unroll
    for (int off = 32; off; off >>= 1) s += __shfl_down(s, off, 64);
    if (lane == 0) {
        float c1, c2;
        if (m == 0)      { c1 = cross[0 * NTOT + i]; c2 = cross[1 * NTOT + i]; }
        else if (m == 1) { c1 = cross[0 * NTOT + i]; c2 = cross[2 * NTOT + i]; }
        else             { c1 = cross[1 * NTOT + i]; c2 = cross[2 * NTOT + i]; }
        dinv[r] = 1.0f / sqrtf(s + c1 + c2);
    }
}

// ---------- prep: x -> bf16 ----------
__global__ void k_tobf16(const float* __restrict__ a, const float* __restrict__ v,
                         const float* __restrict__ xl, unsigned short* __restrict__ xb) {
    size_t e = ((size_t)blockIdx.x * 256 + threadIdx.x) * 4;
    const float* s = (e < SEG) ? a : (e < 2 * SEG) ? v : xl;
    size_t le = (e < SEG) ? e : (e < 2 * SEG) ? e - SEG : e - 2 * SEG;
    float4 x = *(const float4*)(s + le);
    ushort4 y;
    y.x = f2bf(x.x); y.y = f2bf(x.y); y.z = f2bf(x.z); y.w = f2bf(x.w);
    *(ushort4*)(xb + e) = y;
}

// ---------- prep: W -> bf16, transposed to [n][k] ----------
__global__ void k_wt(const float* __restrict__ W0, const float* __restrict__ Wg,
                     unsigned short* __restrict__ Wt) {
    __shared__ float tile[32][33];
    int bx = blockIdx.x, by = blockIdx.y, mm = blockIdx.z;
    const float* W = (mm == 0) ? W0 : Wg + (size_t)(mm - 1) * DD * DD;
    int t = threadIdx.x;
    int tx = t & 31, ty = t >> 5;   // ty 0..7
#pragma unroll
    for (int q = 0; q < 4; q++) {
        int k = by * 32 + ty + q * 8;
        tile[ty + q * 8][tx] = W[(size_t)k * DD + bx * 32 + tx];
    }
    __syncthreads();
#pragma unroll
    for (int q = 0; q < 4; q++) {
        int n = bx * 32 + ty + q * 8;
        Wt[(size_t)mm * DD * DD + (size_t)n * DD + by * 32 + tx] = f2bf(tile[tx][ty + q * 8]);
    }
}

// ---------- K6: bf16 MFMA GEMM [9216x512]@[512x512] ----------
// mode 0: out = relu(acc + bias[col]);  mode 1: out = relu(theta*acc + (1-theta)*bf2f(resid))
__global__ __launch_bounds__(256) void k_gemm_mfma(
    const unsigned short* __restrict__ A, const unsigned short* __restrict__ Wt,
    const float* __restrict__ bias, const unsigned short* __restrict__ resid,
    float* __restrict__ out, float theta, int mode)
{
    __shared__ __align__(16) unsigned short As[128 * 32];
    __shared__ __align__(16) unsigned short Bs[128 * 32];
    int t = threadIdx.x;
    int lane = t & 63, wv = t >> 6;
    int wm = wv & 1, wn = wv >> 1;
    int mbase = blockIdx.y * 128, nbase = blockIdx.x * 128;
    int srow = lane >> 2;          // 0..15
    int scol = (lane & 3) * 8;     // ushort offset within 32-wide K slice
    f32x4 acc[16];
#pragma unroll
    for (int i = 0; i < 16; i++) acc[i] = (f32x4){0.f, 0.f, 0.f, 0.f};

    int q0 = wv * 2, q1 = wv * 2 + 1;
    const unsigned short* Ag0 = A + (size_t)(mbase + q0 * 16 + srow) * DD + scol;
    const unsigned short* Ag1 = A + (size_t)(mbase + q1 * 16 + srow) * DD + scol;
    const unsigned short* Bg0 = Wt + (size_t)(nbase + q0 * 16 + srow) * DD + scol;
    const unsigned short* Bg1 = Wt + (size_t)(nbase + q1 * 16 + srow) * DD + scol;
    unsigned short* Asl0 = &As[q0 * 512];   // wave-uniform LDS bases
    unsigned short* Asl1 = &As[q1 * 512];
    unsigned short* Bsl0 = &Bs[q0 * 512];
    unsigned short* Bsl1 = &Bs[q1 * 512];

    int a_off = (wm * 64 + (lane & 15)) * 32 + (lane >> 4) * 8;
    int b_off = (wn * 64 + (lane & 15)) * 32 + (lane >> 4) * 8;

    for (int kt = 0; kt < DD; kt += 32) {
        __syncthreads();
        gload16(Ag0 + kt, Asl0);
        gload16(Ag1 + kt, Asl1);
        gload16(Bg0 + kt, Bsl0);
        gload16(Bg1 + kt, Bsl1);
        __syncthreads();           // drains vmcnt before any wave reads LDS
        frag8 af[4], bfr[4];
#pragma unroll
        for (int i = 0; i < 4; i++) af[i] = *(const frag8*)&As[a_off + i * 512];
#pragma unroll
        for (int j = 0; j < 4; j++) bfr[j] = *(const frag8*)&Bs[b_off + j * 512];
#pragma unroll
        for (int i = 0; i < 4; i++)
#pragma unroll
            for (int j = 0; j < 4; j++)
                acc[i * 4 + j] = __builtin_amdgcn_mfma_f32_16x16x32_bf16(
                    af[i], bfr[j], acc[i * 4 + j], 0, 0, 0);
    }

    int col0 = nbase + wn * 64 + (lane & 15);
    int row00 = mbase + wm * 64 + ((lane >> 4) << 2);
    float omt = 1.0f - theta;
#pragma unroll
    for (int i = 0; i < 4; i++)
#pragma unroll
        for (int j = 0; j < 4; j++) {
            int col = col0 + j * 16;
            int rowb = row00 + i * 16;
            f32x4 r = acc[i * 4 + j];
#pragma unroll
            for (int rr = 0; rr < 4; rr++) {
                float vv = r[rr];
                size_t o = (size_t)(rowb + rr) * DD + col;
                if (mode == 0) vv += bias[col];
                else vv = theta * vv + omt * bf2f(resid[o]);
                out[o] = fmaxf(vv, 0.f);
            }
        }
}

// ---------- K7: sparse adj @ h -> supb = bf16(0.9*hi + 0.1*h0) ----------
__global__ __launch_bounds__(256) void k_adjmul(
    const float* __restrict__ blk, const float* __restrict__ cross,
    const float* __restrict__ dinv, const float* __restrict__ h,
    const float* __restrict__ h0, unsigned short* __restrict__ supb) {
    __shared__ float Ab[64][64];
    __shared__ float4 hs[64][32];
    int cc = blockIdx.x;
    int d = blockIdx.y, m = blockIdx.z;
    int dbase = d * 64, cb = cc * 128;
    int t = threadIdx.x;
    size_t bbase = (size_t)(m * N_DIA + d) * 4096;
#pragma unroll
    for (int q = 0; q < 16; q++) {
        int e = t + 256 * q;
        int i = e >> 6, j = e & 63;
        Ab[i][j] = blk[bbase + e] * dinv[m * NTOT + dbase + i] * dinv[m * NTOT + dbase + j];
    }
#pragma unroll
    for (int q = 0; q < 8; q++) {
        int f4 = t + 256 * q;
        int j = f4 >> 5, c4 = f4 & 31;
        hs[j][c4] = *(const float4*)(h + (size_t)(m * NTOT + dbase + j) * DD + cb + c4 * 4);
    }
    __syncthreads();
    int tx = t & 31, ty = t >> 5;
    float4 acc[8];
#pragma unroll
    for (int i = 0; i < 8; i++) acc[i] = make_float4(0.f, 0.f, 0.f, 0.f);
    for (int j = 0; j < 64; j++) {
        float4 b = hs[j][tx];
#pragma unroll
        for (int rr = 0; rr < 8; rr++) {
            float aw = Ab[ty * 8 + rr][j];
            acc[rr].x += aw * b.x; acc[rr].y += aw * b.y;
            acc[rr].z += aw * b.z; acc[rr].w += aw * b.w;
        }
    }
#pragma unroll
    for (int rr = 0; rr < 8; rr++) {
        int i = ty * 8 + rr;
        int gi = dbase + i;
        float dm = dinv[m * NTOT + gi];
#pragma unroll
        for (int n = 0; n < 3; n++) {
            if (n == m) continue;
            int p = m + n - 1;
            float cval = cross[p * NTOT + gi] * dm * dinv[n * NTOT + gi];
            float4 hv = *(const float4*)(h + (size_t)(n * NTOT + gi) * DD + cb + tx * 4);
            acc[rr].x += cval * hv.x; acc[rr].y += cval * hv.y;
            acc[rr].z += cval * hv.z; acc[rr].w += cval * hv.w;
        }
        size_t o = (size_t)(m * NTOT + gi) * DD + cb + tx * 4;
        float4 h0v = *(const float4*)(h0 + o);
        ushort4 w;
        w.x = f2bf(0.9f * acc[rr].x + 0.1f * h0v.x);
        w.y = f2bf(0.9f * acc[rr].y + 0.1f * h0v.y);
        w.z = f2bf(0.9f * acc[rr].z + 0.1f * h0v.z);
        w.w = f2bf(0.9f * acc[rr].w + 0.1f * h0v.w);
        *(ushort4*)(supb + o) = w;
    }
}

// ---------- K8: assemble output ----------
__global__ void k_out(const float* __restrict__ a, const float* __restrict__ v,
                      const float* __restrict__ xl, const float* __restrict__ h,
                      float* __restrict__ out) {
    int i = blockIdx.x, t = threadIdx.x;
#pragma unroll
    for (int q = 0; q < 3; q++) {
        int f4 = t + 256 * q;
        int c = f4 * 4;
        int m = c >> 10;
        int ccol = c & 1023;
        float4 val;
        if (ccol < 512) {
            const float* src = (m == 0) ? a : (m == 1) ? v : xl;
            val = *(const float4*)(src + (size_t)i * DD + ccol);
        } else {
            val = *(const float4*)(h + (size_t)(m * NTOT + i) * DD + (ccol - 512));
        }
        *(float4*)(out + (size_t)i * 3072 + c) = val;
    }
}

extern "C" void kernel_launch(void* const* d_in, const int* in_sizes, int n_in,
                              void* d_out, int out_size, void* d_ws, size_t ws_size,
                              hipStream_t stream) {
    (void)in_sizes; (void)n_in; (void)out_size;
    const float* a     = (const float*)d_in[0];
    const float* v     = (const float*)d_in[1];
    const float* l     = (const float*)d_in[2];
    const float* qmask = (const float*)d_in[3];
    const float* Wspk  = (const float*)d_in[5];
    const float* W0    = (const float*)d_in[6];
    const float* b0    = (const float*)d_in[7];
    const float* Wg    = (const float*)d_in[8];
    float* out = (float*)d_out;
    float* ws = (float*)d_ws;

    const size_t big = SEG * 3;                        // 4,718,592 floats
    float* xl    = ws;                                 // SEG
    float* invn  = xl + SEG;                           // M3
    float* blk   = invn + M3;                          // 589,824
    float* cross = blk + (size_t)3 * N_DIA * 4096;     // M3
    float* dinvp = cross + M3;                         // M3
    unsigned short* Wt = (unsigned short*)(dinvp + M3);          // 786,432 us = 393,216 f
    unsigned short* xb = (unsigned short*)((float*)(dinvp + M3) + 393216); // 4,718,592 us
    unsigned short* supb = xb;                         // aliased: xb dead after gemm0
    float* h  = (float*)xb + big / 2;                  // big floats
    float* hend = h + big;
    size_t used = (size_t)(hend - ws);
    // h0: in ws if room, else parked in d_out (fully rewritten by k_out at the end)
    float* h0 = (ws_size >= (used + big) * sizeof(float)) ? hend : out;

    k_xl     <<<NTOT, 128, 0, stream>>>(l, qmask, Wspk, xl);
    k_invnorm<<<M3, 64, 0, stream>>>(a, v, xl, invn);
    k_gram   <<<dim3(N_DIA, 3), 256, 0, stream>>>(a, v, xl, invn, blk);
    k_cross  <<<M3, 64, 0, stream>>>(a, v, xl, invn, cross);
    k_dinv   <<<M3, 64, 0, stream>>>(blk, cross, dinvp);
    k_tobf16 <<<(int)(3 * SEG / 4 / 256), 256, 0, stream>>>(a, v, xl, xb);
    k_wt     <<<dim3(16, 16, 3), 256, 0, stream>>>(W0, Wg, Wt);

    // h0 = relu(x @ W0 + b0)
    k_gemm_mfma<<<dim3(4, 72), 256, 0, stream>>>(xb, Wt, b0, xb, h0, 0.f, 0);

    const float th1 = 0.40546510810816438f;  // log(1.5)
    const float th2 = 0.22314355131420976f;  // log(1.25)

    // layer 1
    k_adjmul<<<dim3(4, N_DIA, 3), 256, 0, stream>>>(blk, cross, dinvp, h0, h0, supb);
    k_gemm_mfma<<<dim3(4, 72), 256, 0, stream>>>(supb, Wt + (size_t)DD * DD, b0, supb, h, th1, 1);
    // layer 2
    k_adjmul<<<dim3(4, N_DIA, 3), 256, 0, stream>>>(blk, cross, dinvp, h, h0, supb);
    k_gemm_mfma<<<dim3(4, 72), 256, 0, stream>>>(supb, Wt + (size_t)2 * DD * DD, b0, supb, h, th2, 1);

    k_out<<<NTOT, 256, 0, stream>>>(a, v, xl, h, out);
}

// Round 4
// 244.977 us; speedup vs baseline: 1.7478x; 1.1452x over previous
//
#include <hip/hip_runtime.h>
#include <math.h>

#define N_DIA 48
#define NTOT  3072     // N utterances
#define DD    512      // D == H
#define M3    9216     // 3N
#define SEG   ((size_t)NTOT * DD)

#define SCALE_F 0.99999f
#define PI_F    3.14159274101257324f

typedef __attribute__((ext_vector_type(8))) short frag8;
typedef __attribute__((ext_vector_type(4))) float f32x4;

__device__ __forceinline__ float ang_sim(float cs) {
    float cc = cs * SCALE_F;
    cc = fminf(fmaxf(cc, -SCALE_F), SCALE_F);
    return 1.0f - acosf(cc) / PI_F;
}
__device__ __forceinline__ unsigned short f2bf(float x) {
    union { float f; unsigned int u; } c; c.f = x;
    unsigned int r = c.u + 0x7fffu + ((c.u >> 16) & 1u);
    return (unsigned short)(r >> 16);
}
__device__ __forceinline__ float bf2f(unsigned short h) {
    union { unsigned int u; float f; } c; c.u = ((unsigned int)h) << 16;
    return c.f;
}
__device__ __forceinline__ void gload16(const unsigned short* g, unsigned short* s) {
    __builtin_amdgcn_global_load_lds(
        (const __attribute__((address_space(1))) unsigned int*)g,
        (__attribute__((address_space(3))) unsigned int*)s, 16, 0, 0);
}

// ---------- K1: xl = l + W_spk[argmax(qmask)] ----------
__global__ void k_xl(const float* __restrict__ l, const float* __restrict__ qmask,
                     const float* __restrict__ Wspk, float* __restrict__ xl) {
    int i = blockIdx.x;
    int pos = i & 63, dia = i >> 6;
    int qb = (pos * N_DIA + dia) * 2;
    float q0 = qmask[qb], q1 = qmask[qb + 1];
    int spk = (q0 >= q1) ? 0 : 1;
    const float4* lv = (const float4*)(l + (size_t)i * DD);
    const float4* wv = (const float4*)(Wspk + (size_t)spk * DD);
    float4* ov = (float4*)(xl + (size_t)i * DD);
    int t = threadIdx.x;
    float4 a = lv[t], b = wv[t];
    ov[t] = make_float4(a.x + b.x, a.y + b.y, a.z + b.z, a.w + b.w);
}

// ---------- K2: inverse L2 norms ----------
__global__ void k_invnorm(const float* __restrict__ a, const float* __restrict__ v,
                          const float* __restrict__ xl, float* __restrict__ invn) {
    int r = blockIdx.x;
    int m = r / NTOT, i = r % NTOT;
    const float* src = (m == 0) ? a : (m == 1) ? v : xl;
    const float4* p = (const float4*)(src + (size_t)i * DD);
    int lane = threadIdx.x;
    float s = 0.f;
#pragma unroll
    for (int e = 0; e < 2; e++) {
        float4 x = p[lane * 2 + e];
        s += x.x * x.x + x.y * x.y + x.z * x.z + x.w * x.w;
    }
#pragma unroll
    for (int off = 32; off; off >>= 1) s += __shfl_down(s, off, 64);
    if (lane == 0) invn[r] = 1.0f / sqrtf(s);
}

// ---------- K3: per-dialogue 64x64 angular-sim Gram blocks via MFMA ----------
// dot of unnormalized bf16 rows, normalized by invn in the epilogue.
__global__ __launch_bounds__(256) void k_gram_mfma(
    const unsigned short* __restrict__ xb, const float* __restrict__ invn,
    float* __restrict__ blk)
{
    __shared__ __align__(16) unsigned short Xs[16 * 2048];   // 64 KB: 16 K-chunks of 64x32
    int d = blockIdx.x, m = blockIdx.y;
    int t = threadIdx.x;
    int lane = t & 63, wv = t >> 6;
    int mrow = m * NTOT + d * 64;                 // first global row of this segment
    const unsigned short* src = xb + (size_t)mrow * DD;

    // stage 64 rows x 512 K (bf16) -> LDS, row-major per 32-K chunk
#pragma unroll
    for (int c = 0; c < 16; c++) {
        gload16(src + (size_t)(t >> 2) * DD + c * 32 + (t & 3) * 8,
                &Xs[c * 2048 + wv * 512]);
    }
    __syncthreads();

    int rsel = lane & 15, quad = lane >> 4;
    f32x4 acc[4];
#pragma unroll
    for (int j = 0; j < 4; j++) acc[j] = (f32x4){0.f, 0.f, 0.f, 0.f};

#pragma unroll
    for (int c = 0; c < 16; c++) {
        const unsigned short* base = &Xs[c * 2048];
        frag8 bf[4];
#pragma unroll
        for (int j = 0; j < 4; j++)
            bf[j] = *(const frag8*)&base[(j * 16 + rsel) * 32 + quad * 8];
        frag8 af = *(const frag8*)&base[(wv * 16 + rsel) * 32 + quad * 8];
#pragma unroll
        for (int j = 0; j < 4; j++)
            acc[j] = __builtin_amdgcn_mfma_f32_16x16x32_bf16(af, bf[j], acc[j], 0, 0, 0);
    }

    // epilogue: sim = ang_sim(dot * invn_row * invn_col)
    size_t bbase = (size_t)(m * N_DIA + d) * 4096;
    int rowl0 = wv * 16 + quad * 4;
    float ir[4];
#pragma unroll
    for (int r = 0; r < 4; r++) ir[r] = invn[mrow + rowl0 + r];
#pragma unroll
    for (int j = 0; j < 4; j++) {
        int coll = j * 16 + rsel;
        float ic = invn[mrow + coll];
#pragma unroll
        for (int r = 0; r < 4; r++) {
            float sim = ang_sim(acc[j][r] * ir[r] * ic);
            blk[bbase + (size_t)(rowl0 + r) * 64 + coll] = sim;
        }
    }
}

// ---------- K4: cross-modality diagonal sims ----------
__global__ void k_cross(const float* __restrict__ a, const float* __restrict__ v,
                        const float* __restrict__ xl, const float* __restrict__ invn,
                        float* __restrict__ cross) {
    int r = blockIdx.x;
    int p = r / NTOT, i = r % NTOT;
    const float *s1, *s2; int m1, m2;
    if (p == 0)      { s1 = a; s2 = v;  m1 = 0; m2 = 1; }
    else if (p == 1) { s1 = a; s2 = xl; m1 = 0; m2 = 2; }
    else             { s1 = v; s2 = xl; m1 = 1; m2 = 2; }
    int lane = threadIdx.x;
    const float4* p1 = (const float4*)(s1 + (size_t)i * DD);
    const float4* p2 = (const float4*)(s2 + (size_t)i * DD);
    float s = 0.f;
#pragma unroll
    for (int e = 0; e < 2; e++) {
        float4 x = p1[lane * 2 + e], y = p2[lane * 2 + e];
        s += x.x * y.x + x.y * y.y + x.z * y.z + x.w * y.w;
    }
#pragma unroll
    for (int off = 32; off; off >>= 1) s += __shfl_down(s, off, 64);
    if (lane == 0) {
        float cs = s * invn[m1 * NTOT + i] * invn[m2 * NTOT + i];
        cross[r] = ang_sim(cs);
    }
}

// ---------- K5: degree -> dinv ----------
__global__ void k_dinv(const float* __restrict__ blk, const float* __restrict__ cross,
                       float* __restrict__ dinv) {
    int r = blockIdx.x;
    int m = r / NTOT, i = r % NTOT;
    int d = i >> 6, ir = i & 63;
    int lane = threadIdx.x;
    float s = blk[((size_t)(m * N_DIA + d) * 64 + ir) * 64 + lane];
#pragma unroll
    for (int off = 32; off; off >>= 1) s += __shfl_down(s, off, 64);
    if (lane == 0) {
        float c1, c2;
        if (m == 0)      { c1 = cross[0 * NTOT + i]; c2 = cross[1 * NTOT + i]; }
        else if (m == 1) { c1 = cross[0 * NTOT + i]; c2 = cross[2 * NTOT + i]; }
        else             { c1 = cross[1 * NTOT + i]; c2 = cross[2 * NTOT + i]; }
        dinv[r] = 1.0f / sqrtf(s + c1 + c2);
    }
}

// ---------- prep: x -> bf16 ----------
__global__ void k_tobf16(const float* __restrict__ a, const float* __restrict__ v,
                         const float* __restrict__ xl, unsigned short* __restrict__ xb) {
    size_t e = ((size_t)blockIdx.x * 256 + threadIdx.x) * 4;
    const float* s = (e < SEG) ? a : (e < 2 * SEG) ? v : xl;
    size_t le = (e < SEG) ? e : (e < 2 * SEG) ? e - SEG : e - 2 * SEG;
    float4 x = *(const float4*)(s + le);
    ushort4 y;
    y.x = f2bf(x.x); y.y = f2bf(x.y); y.z = f2bf(x.z); y.w = f2bf(x.w);
    *(ushort4*)(xb + e) = y;
}

// ---------- prep: W -> bf16, transposed to [n][k] ----------
__global__ void k_wt(const float* __restrict__ W0, const float* __restrict__ Wg,
                     unsigned short* __restrict__ Wt) {
    __shared__ float tile[32][33];
    int bx = blockIdx.x, by = blockIdx.y, mm = blockIdx.z;
    const float* W = (mm == 0) ? W0 : Wg + (size_t)(mm - 1) * DD * DD;
    int t = threadIdx.x;
    int tx = t & 31, ty = t >> 5;   // ty 0..7
#pragma unroll
    for (int q = 0; q < 4; q++) {
        int k = by * 32 + ty + q * 8;
        tile[ty + q * 8][tx] = W[(size_t)k * DD + bx * 32 + tx];
    }
    __syncthreads();
#pragma unroll
    for (int q = 0; q < 4; q++) {
        int n = bx * 32 + ty + q * 8;
        Wt[(size_t)mm * DD * DD + (size_t)n * DD + by * 32 + tx] = f2bf(tile[tx][ty + q * 8]);
    }
}

// ---------- K6: bf16 MFMA GEMM [9216x512]@[512x512] ----------
// mode 0: out = relu(acc + bias[col]);  mode 1: out = relu(theta*acc + (1-theta)*bf2f(resid))
__global__ __launch_bounds__(256) void k_gemm_mfma(
    const unsigned short* __restrict__ A, const unsigned short* __restrict__ Wt,
    const float* __restrict__ bias, const unsigned short* __restrict__ resid,
    float* __restrict__ out, float theta, int mode)
{
    __shared__ __align__(16) unsigned short As[128 * 32];
    __shared__ __align__(16) unsigned short Bs[128 * 32];
    int t = threadIdx.x;
    int lane = t & 63, wv = t >> 6;
    int wm = wv & 1, wn = wv >> 1;
    int mbase = blockIdx.y * 128, nbase = blockIdx.x * 128;
    int srow = lane >> 2;          // 0..15
    int scol = (lane & 3) * 8;     // ushort offset within 32-wide K slice
    f32x4 acc[16];
#pragma unroll
    for (int i = 0; i < 16; i++) acc[i] = (f32x4){0.f, 0.f, 0.f, 0.f};

    int q0 = wv * 2, q1 = wv * 2 + 1;
    const unsigned short* Ag0 = A + (size_t)(mbase + q0 * 16 + srow) * DD + scol;
    const unsigned short* Ag1 = A + (size_t)(mbase + q1 * 16 + srow) * DD + scol;
    const unsigned short* Bg0 = Wt + (size_t)(nbase + q0 * 16 + srow) * DD + scol;
    const unsigned short* Bg1 = Wt + (size_t)(nbase + q1 * 16 + srow) * DD + scol;
    unsigned short* Asl0 = &As[q0 * 512];   // wave-uniform LDS bases
    unsigned short* Asl1 = &As[q1 * 512];
    unsigned short* Bsl0 = &Bs[q0 * 512];
    unsigned short* Bsl1 = &Bs[q1 * 512];

    int a_off = (wm * 64 + (lane & 15)) * 32 + (lane >> 4) * 8;
    int b_off = (wn * 64 + (lane & 15)) * 32 + (lane >> 4) * 8;

    for (int kt = 0; kt < DD; kt += 32) {
        __syncthreads();
        gload16(Ag0 + kt, Asl0);
        gload16(Ag1 + kt, Asl1);
        gload16(Bg0 + kt, Bsl0);
        gload16(Bg1 + kt, Bsl1);
        __syncthreads();           // drains vmcnt before any wave reads LDS
        frag8 af[4], bfr[4];
#pragma unroll
        for (int i = 0; i < 4; i++) af[i] = *(const frag8*)&As[a_off + i * 512];
#pragma unroll
        for (int j = 0; j < 4; j++) bfr[j] = *(const frag8*)&Bs[b_off + j * 512];
#pragma unroll
        for (int i = 0; i < 4; i++)
#pragma unroll
            for (int j = 0; j < 4; j++)
                acc[i * 4 + j] = __builtin_amdgcn_mfma_f32_16x16x32_bf16(
                    af[i], bfr[j], acc[i * 4 + j], 0, 0, 0);
    }

    int col0 = nbase + wn * 64 + (lane & 15);
    int row00 = mbase + wm * 64 + ((lane >> 4) << 2);
    float omt = 1.0f - theta;
#pragma unroll
    for (int i = 0; i < 4; i++)
#pragma unroll
        for (int j = 0; j < 4; j++) {
            int col = col0 + j * 16;
            int rowb = row00 + i * 16;
            f32x4 r = acc[i * 4 + j];
#pragma unroll
            for (int rr = 0; rr < 4; rr++) {
                float vv = r[rr];
                size_t o = (size_t)(rowb + rr) * DD + col;
                if (mode == 0) vv += bias[col];
                else vv = theta * vv + omt * bf2f(resid[o]);
                out[o] = fmaxf(vv, 0.f);
            }
        }
}

// ---------- K7: sparse adj @ h -> supb = bf16(0.9*hi + 0.1*h0) ----------
__global__ __launch_bounds__(256) void k_adjmul(
    const float* __restrict__ blk, const float* __restrict__ cross,
    const float* __restrict__ dinv, const float* __restrict__ h,
    const float* __restrict__ h0, unsigned short* __restrict__ supb) {
    __shared__ float Ab[64][64];
    __shared__ float4 hs[64][32];
    int cc = blockIdx.x;
    int d = blockIdx.y, m = blockIdx.z;
    int dbase = d * 64, cb = cc * 128;
    int t = threadIdx.x;
    size_t bbase = (size_t)(m * N_DIA + d) * 4096;
#pragma unroll
    for (int q = 0; q < 16; q++) {
        int e = t + 256 * q;
        int i = e >> 6, j = e & 63;
        Ab[i][j] = blk[bbase + e] * dinv[m * NTOT + dbase + i] * dinv[m * NTOT + dbase + j];
    }
#pragma unroll
    for (int q = 0; q < 8; q++) {
        int f4 = t + 256 * q;
        int j = f4 >> 5, c4 = f4 & 31;
        hs[j][c4] = *(const float4*)(h + (size_t)(m * NTOT + dbase + j) * DD + cb + c4 * 4);
    }
    __syncthreads();
    int tx = t & 31, ty = t >> 5;
    float4 acc[8];
#pragma unroll
    for (int i = 0; i < 8; i++) acc[i] = make_float4(0.f, 0.f, 0.f, 0.f);
    for (int j = 0; j < 64; j++) {
        float4 b = hs[j][tx];
#pragma unroll
        for (int rr = 0; rr < 8; rr++) {
            float aw = Ab[ty * 8 + rr][j];
            acc[rr].x += aw * b.x; acc[rr].y += aw * b.y;
            acc[rr].z += aw * b.z; acc[rr].w += aw * b.w;
        }
    }
#pragma unroll
    for (int rr = 0; rr < 8; rr++) {
        int i = ty * 8 + rr;
        int gi = dbase + i;
        float dm = dinv[m * NTOT + gi];
#pragma unroll
        for (int n = 0; n < 3; n++) {
            if (n == m) continue;
            int p = m + n - 1;
            float cval = cross[p * NTOT + gi] * dm * dinv[n * NTOT + gi];
            float4 hv = *(const float4*)(h + (size_t)(n * NTOT + gi) * DD + cb + tx * 4);
            acc[rr].x += cval * hv.x; acc[rr].y += cval * hv.y;
            acc[rr].z += cval * hv.z; acc[rr].w += cval * hv.w;
        }
        size_t o = (size_t)(m * NTOT + gi) * DD + cb + tx * 4;
        float4 h0v = *(const float4*)(h0 + o);
        ushort4 w;
        w.x = f2bf(0.9f * acc[rr].x + 0.1f * h0v.x);
        w.y = f2bf(0.9f * acc[rr].y + 0.1f * h0v.y);
        w.z = f2bf(0.9f * acc[rr].z + 0.1f * h0v.z);
        w.w = f2bf(0.9f * acc[rr].w + 0.1f * h0v.w);
        *(ushort4*)(supb + o) = w;
    }
}

// ---------- K8: assemble output ----------
__global__ void k_out(const float* __restrict__ a, const float* __restrict__ v,
                      const float* __restrict__ xl, const float* __restrict__ h,
                      float* __restrict__ out) {
    int i = blockIdx.x, t = threadIdx.x;
#pragma unroll
    for (int q = 0; q < 3; q++) {
        int f4 = t + 256 * q;
        int c = f4 * 4;
        int m = c >> 10;
        int ccol = c & 1023;
        float4 val;
        if (ccol < 512) {
            const float* src = (m == 0) ? a : (m == 1) ? v : xl;
            val = *(const float4*)(src + (size_t)i * DD + ccol);
        } else {
            val = *(const float4*)(h + (size_t)(m * NTOT + i) * DD + (ccol - 512));
        }
        *(float4*)(out + (size_t)i * 3072 + c) = val;
    }
}

extern "C" void kernel_launch(void* const* d_in, const int* in_sizes, int n_in,
                              void* d_out, int out_size, void* d_ws, size_t ws_size,
                              hipStream_t stream) {
    (void)in_sizes; (void)n_in; (void)out_size;
    const float* a     = (const float*)d_in[0];
    const float* v     = (const float*)d_in[1];
    const float* l     = (const float*)d_in[2];
    const float* qmask = (const float*)d_in[3];
    const float* Wspk  = (const float*)d_in[5];
    const float* W0    = (const float*)d_in[6];
    const float* b0    = (const float*)d_in[7];
    const float* Wg    = (const float*)d_in[8];
    float* out = (float*)d_out;
    float* ws = (float*)d_ws;

    const size_t big = SEG * 3;                        // 4,718,592 floats
    float* xl    = ws;                                 // SEG
    float* invn  = xl + SEG;                           // M3
    float* blk   = invn + M3;                          // 589,824
    float* cross = blk + (size_t)3 * N_DIA * 4096;     // M3
    float* dinvp = cross + M3;                         // M3
    unsigned short* Wt = (unsigned short*)(dinvp + M3);          // 786,432 us = 393,216 f
    unsigned short* xb = (unsigned short*)((float*)(dinvp + M3) + 393216); // 4,718,592 us
    unsigned short* supb = xb;                         // aliased: xb dead after gemm0
    float* h  = (float*)xb + big / 2;                  // big floats
    float* hend = h + big;
    size_t used = (size_t)(hend - ws);
    // h0: in ws if room, else parked in d_out (fully rewritten by k_out at the end)
    float* h0 = (ws_size >= (used + big) * sizeof(float)) ? hend : out;

    k_xl     <<<NTOT, 128, 0, stream>>>(l, qmask, Wspk, xl);
    k_invnorm<<<M3, 64, 0, stream>>>(a, v, xl, invn);
    k_tobf16 <<<(int)(3 * SEG / 4 / 256), 256, 0, stream>>>(a, v, xl, xb);
    k_gram_mfma<<<dim3(N_DIA, 3), 256, 0, stream>>>(xb, invn, blk);
    k_cross  <<<M3, 64, 0, stream>>>(a, v, xl, invn, cross);
    k_dinv   <<<M3, 64, 0, stream>>>(blk, cross, dinvp);
    k_wt     <<<dim3(16, 16, 3), 256, 0, stream>>>(W0, Wg, Wt);

    // h0 = relu(x @ W0 + b0)
    k_gemm_mfma<<<dim3(4, 72), 256, 0, stream>>>(xb, Wt, b0, xb, h0, 0.f, 0);

    const float th1 = 0.40546510810816438f;  // log(1.5)
    const float th2 = 0.22314355131420976f;  // log(1.25)

    // layer 1
    k_adjmul<<<dim3(4, N_DIA, 3), 256, 0, stream>>>(blk, cross, dinvp, h0, h0, supb);
    k_gemm_mfma<<<dim3(4, 72), 256, 0, stream>>>(supb, Wt + (size_t)DD * DD, b0, supb, h, th1, 1);
    // layer 2
    k_adjmul<<<dim3(4, N_DIA, 3), 256, 0, stream>>>(blk, cross, dinvp, h, h0, supb);
    k_gemm_mfma<<<dim3(4, 72), 256, 0, stream>>>(supb, Wt + (size_t)2 * DD * DD, b0, supb, h, th2, 1);

    k_out<<<NTOT, 256, 0, stream>>>(a, v, xl, h, out);
}

// Round 6
// 234.056 us; speedup vs baseline: 1.8294x; 1.0467x over previous
//
#include <hip/hip_runtime.h>
#include <math.h>

#define N_DIA 48
#define NTOT  3072     // N utterances
#define DD    512      // D == H
#define M3    9216     // 3N
#define SEG   ((size_t)NTOT * DD)

#define SCALE_F 0.99999f
#define PI_F    3.14159274101257324f

typedef __attribute__((ext_vector_type(8))) short frag8;
typedef __attribute__((ext_vector_type(4))) float f32x4;

__device__ __forceinline__ float ang_sim(float cs) {
    float cc = cs * SCALE_F;
    cc = fminf(fmaxf(cc, -SCALE_F), SCALE_F);
    return 1.0f - acosf(cc) / PI_F;
}
__device__ __forceinline__ unsigned short f2bf(float x) {
    union { float f; unsigned int u; } c; c.f = x;
    unsigned int r = c.u + 0x7fffu + ((c.u >> 16) & 1u);
    return (unsigned short)(r >> 16);
}
__device__ __forceinline__ float bf2f(unsigned short h) {
    union { unsigned int u; float f; } c; c.u = ((unsigned int)h) << 16;
    return c.f;
}
__device__ __forceinline__ void gload16(const unsigned short* g, unsigned short* s) {
    __builtin_amdgcn_global_load_lds(
        (const __attribute__((address_space(1))) unsigned int*)g,
        (__attribute__((address_space(3))) unsigned int*)s, 16, 0, 0);
}

// ---------- K_pre: xl, bf16 casts, inverse norms, cross-modality sims ----------
__global__ __launch_bounds__(64) void k_pre(
    const float* __restrict__ a, const float* __restrict__ v,
    const float* __restrict__ l, const float* __restrict__ qmask,
    const float* __restrict__ Wspk,
    float* __restrict__ xl, unsigned short* __restrict__ xb,
    float* __restrict__ invn, float* __restrict__ cross)
{
    int i = blockIdx.x, t = threadIdx.x;   // 64 threads = 1 wave
    int pos = i & 63, dia = i >> 6;
    int qb = (pos * N_DIA + dia) * 2;
    float q0 = qmask[qb], q1 = qmask[qb + 1];
    int spk = (q0 >= q1) ? 0 : 1;
    const float4* av4 = (const float4*)(a + (size_t)i * DD);
    const float4* vv4 = (const float4*)(v + (size_t)i * DD);
    const float4* lv4 = (const float4*)(l + (size_t)i * DD);
    const float4* wv4 = (const float4*)(Wspk + (size_t)spk * DD);
    float4* xlo = (float4*)(xl + (size_t)i * DD);
    float saa = 0, svv = 0, sll = 0, sav = 0, sal = 0, svl = 0;
#pragma unroll
    for (int e = 0; e < 2; e++) {
        int idx = t * 2 + e;
        float4 xa = av4[idx], xv = vv4[idx], xd = lv4[idx], xw = wv4[idx];
        float4 xL = make_float4(xd.x + xw.x, xd.y + xw.y, xd.z + xw.z, xd.w + xw.w);
        xlo[idx] = xL;
        ushort4 ya, yv, yl;
        ya.x = f2bf(xa.x); ya.y = f2bf(xa.y); ya.z = f2bf(xa.z); ya.w = f2bf(xa.w);
        yv.x = f2bf(xv.x); yv.y = f2bf(xv.y); yv.z = f2bf(xv.z); yv.w = f2bf(xv.w);
        yl.x = f2bf(xL.x); yl.y = f2bf(xL.y); yl.z = f2bf(xL.z); yl.w = f2bf(xL.w);
        *(ushort4*)(xb + (size_t)i * DD + idx * 4) = ya;
        *(ushort4*)(xb + SEG + (size_t)i * DD + idx * 4) = yv;
        *(ushort4*)(xb + 2 * SEG + (size_t)i * DD + idx * 4) = yl;
        saa += xa.x * xa.x + xa.y * xa.y + xa.z * xa.z + xa.w * xa.w;
        svv += xv.x * xv.x + xv.y * xv.y + xv.z * xv.z + xv.w * xv.w;
        sll += xL.x * xL.x + xL.y * xL.y + xL.z * xL.z + xL.w * xL.w;
        sav += xa.x * xv.x + xa.y * xv.y + xa.z * xv.z + xa.w * xv.w;
        sal += xa.x * xL.x + xa.y * xL.y + xa.z * xL.z + xa.w * xL.w;
        svl += xv.x * xL.x + xv.y * xL.y + xv.z * xL.z + xv.w * xL.w;
    }
#pragma unroll
    for (int off = 32; off; off >>= 1) {
        saa += __shfl_down(saa, off, 64);
        svv += __shfl_down(svv, off, 64);
        sll += __shfl_down(sll, off, 64);
        sav += __shfl_down(sav, off, 64);
        sal += __shfl_down(sal, off, 64);
        svl += __shfl_down(svl, off, 64);
    }
    if (t == 0) {
        float ina = 1.0f / sqrtf(saa);
        float inv_ = 1.0f / sqrtf(svv);
        float inl = 1.0f / sqrtf(sll);
        invn[i] = ina; invn[NTOT + i] = inv_; invn[2 * NTOT + i] = inl;
        cross[i]            = ang_sim(sav * ina * inv_);
        cross[NTOT + i]     = ang_sim(sal * ina * inl);
        cross[2 * NTOT + i] = ang_sim(svl * inv_ * inl);
    }
}

// ---------- gram (MFMA) + fused dinv ----------
__global__ __launch_bounds__(256) void k_gram_mfma(
    const unsigned short* __restrict__ xb, const float* __restrict__ invn,
    const float* __restrict__ cross, float* __restrict__ blk,
    float* __restrict__ dinv)
{
    __shared__ __align__(16) unsigned short Xs[16 * 2048];   // 64 KB
    int d = blockIdx.x, m = blockIdx.y;
    int t = threadIdx.x;
    int lane = t & 63, wv = t >> 6;
    int mrow = m * NTOT + d * 64;
    const unsigned short* src = xb + (size_t)mrow * DD;
#pragma unroll
    for (int c = 0; c < 16; c++) {
        gload16(src + (size_t)(t >> 2) * DD + c * 32 + (t & 3) * 8,
                &Xs[c * 2048 + wv * 512]);
    }
    __syncthreads();

    int rsel = lane & 15, quad = lane >> 4;
    f32x4 acc[4];
#pragma unroll
    for (int j = 0; j < 4; j++) acc[j] = (f32x4){0.f, 0.f, 0.f, 0.f};
#pragma unroll
    for (int c = 0; c < 16; c++) {
        const unsigned short* base = &Xs[c * 2048];
        frag8 bf[4];
#pragma unroll
        for (int j = 0; j < 4; j++)
            bf[j] = *(const frag8*)&base[(j * 16 + rsel) * 32 + quad * 8];
        frag8 af = *(const frag8*)&base[(wv * 16 + rsel) * 32 + quad * 8];
#pragma unroll
        for (int j = 0; j < 4; j++)
            acc[j] = __builtin_amdgcn_mfma_f32_16x16x32_bf16(af, bf[j], acc[j], 0, 0, 0);
    }

    size_t bbase = (size_t)(m * N_DIA + d) * 4096;
    int rowl0 = wv * 16 + quad * 4;
    float ir[4], rs[4] = {0.f, 0.f, 0.f, 0.f};
#pragma unroll
    for (int r = 0; r < 4; r++) ir[r] = invn[mrow + rowl0 + r];
#pragma unroll
    for (int j = 0; j < 4; j++) {
        int coll = j * 16 + rsel;
        float ic = invn[mrow + coll];
#pragma unroll
        for (int r = 0; r < 4; r++) {
            float sim = ang_sim(acc[j][r] * ir[r] * ic);
            blk[bbase + (size_t)(rowl0 + r) * 64 + coll] = sim;
            rs[r] += sim;
        }
    }
    // row-degree reduce across the 16 rsel lanes of each quad
#pragma unroll
    for (int off = 8; off; off >>= 1)
#pragma unroll
        for (int r = 0; r < 4; r++) rs[r] += __shfl_down(rs[r], off, 16);
    if (rsel == 0) {
#pragma unroll
        for (int r = 0; r < 4; r++) {
            int gi = d * 64 + rowl0 + r;
            float c1, c2;
            if (m == 0)      { c1 = cross[gi];        c2 = cross[NTOT + gi]; }
            else if (m == 1) { c1 = cross[gi];        c2 = cross[2 * NTOT + gi]; }
            else             { c1 = cross[NTOT + gi]; c2 = cross[2 * NTOT + gi]; }
            dinv[m * NTOT + gi] = 1.0f / sqrtf(rs[r] + c1 + c2);
        }
    }
}

// ---------- prep: W -> bf16, transposed to [n][k] ----------
__global__ void k_wt(const float* __restrict__ W0, const float* __restrict__ Wg,
                     unsigned short* __restrict__ Wt) {
    __shared__ float tile[32][33];
    int bx = blockIdx.x, by = blockIdx.y, mm = blockIdx.z;
    const float* W = (mm == 0) ? W0 : Wg + (size_t)(mm - 1) * DD * DD;
    int t = threadIdx.x;
    int tx = t & 31, ty = t >> 5;
#pragma unroll
    for (int q = 0; q < 4; q++) {
        int k = by * 32 + ty + q * 8;
        tile[ty + q * 8][tx] = W[(size_t)k * DD + bx * 32 + tx];
    }
    __syncthreads();
#pragma unroll
    for (int q = 0; q < 4; q++) {
        int n = bx * 32 + ty + q * 8;
        Wt[(size_t)mm * DD * DD + (size_t)n * DD + by * 32 + tx] = f2bf(tile[tx][ty + q * 8]);
    }
}

// ---------- K6: bf16 MFMA GEMM [9216x512]@[512x512] (r4-proven LDS version) ----------
// mode 0: out = relu(acc + bias[col]);  mode 1: out = relu(theta*acc + (1-theta)*bf2f(resid))
__global__ __launch_bounds__(256) void k_gemm_mfma(
    const unsigned short* __restrict__ A, const unsigned short* __restrict__ Wt,
    const float* __restrict__ bias, const unsigned short* __restrict__ resid,
    float* __restrict__ out, float theta, int mode)
{
    __shared__ __align__(16) unsigned short As[128 * 32];
    __shared__ __align__(16) unsigned short Bs[128 * 32];
    int t = threadIdx.x;
    int lane = t & 63, wv = t >> 6;
    int wm = wv & 1, wn = wv >> 1;
    int mbase = blockIdx.y * 128, nbase = blockIdx.x * 128;
    int srow = lane >> 2;          // 0..15
    int scol = (lane & 3) * 8;     // ushort offset within 32-wide K slice
    f32x4 acc[16];
#pragma unroll
    for (int i = 0; i < 16; i++) acc[i] = (f32x4){0.f, 0.f, 0.f, 0.f};

    int q0 = wv * 2, q1 = wv * 2 + 1;
    const unsigned short* Ag0 = A + (size_t)(mbase + q0 * 16 + srow) * DD + scol;
    const unsigned short* Ag1 = A + (size_t)(mbase + q1 * 16 + srow) * DD + scol;
    const unsigned short* Bg0 = Wt + (size_t)(nbase + q0 * 16 + srow) * DD + scol;
    const unsigned short* Bg1 = Wt + (size_t)(nbase + q1 * 16 + srow) * DD + scol;
    unsigned short* Asl0 = &As[q0 * 512];
    unsigned short* Asl1 = &As[q1 * 512];
    unsigned short* Bsl0 = &Bs[q0 * 512];
    unsigned short* Bsl1 = &Bs[q1 * 512];

    int a_off = (wm * 64 + (lane & 15)) * 32 + (lane >> 4) * 8;
    int b_off = (wn * 64 + (lane & 15)) * 32 + (lane >> 4) * 8;

    for (int kt = 0; kt < DD; kt += 32) {
        __syncthreads();
        gload16(Ag0 + kt, Asl0);
        gload16(Ag1 + kt, Asl1);
        gload16(Bg0 + kt, Bsl0);
        gload16(Bg1 + kt, Bsl1);
        __syncthreads();
        frag8 af[4], bfr[4];
#pragma unroll
        for (int i = 0; i < 4; i++) af[i] = *(const frag8*)&As[a_off + i * 512];
#pragma unroll
        for (int j = 0; j < 4; j++) bfr[j] = *(const frag8*)&Bs[b_off + j * 512];
#pragma unroll
        for (int i = 0; i < 4; i++)
#pragma unroll
            for (int j = 0; j < 4; j++)
                acc[i * 4 + j] = __builtin_amdgcn_mfma_f32_16x16x32_bf16(
                    af[i], bfr[j], acc[i * 4 + j], 0, 0, 0);
    }

    int col0 = nbase + wn * 64 + (lane & 15);
    int row00 = mbase + wm * 64 + ((lane >> 4) << 2);
    float omt = 1.0f - theta;
#pragma unroll
    for (int i = 0; i < 4; i++)
#pragma unroll
        for (int j = 0; j < 4; j++) {
            int col = col0 + j * 16;
            int rowb = row00 + i * 16;
            f32x4 r = acc[i * 4 + j];
#pragma unroll
            for (int rr = 0; rr < 4; rr++) {
                float vv = r[rr];
                size_t o = (size_t)(rowb + rr) * DD + col;
                if (mode == 0) vv += bias[col];
                else vv = theta * vv + omt * bf2f(resid[o]);
                out[o] = fmaxf(vv, 0.f);
            }
        }
}

// ---------- K7: sparse adj @ h (fp32 in) -> supb bf16 (r4-proven + Ab pad) ----------
__global__ __launch_bounds__(256) void k_adjmul(
    const float* __restrict__ blk, const float* __restrict__ cross,
    const float* __restrict__ dinv, const float* __restrict__ h,
    const float* __restrict__ h0, unsigned short* __restrict__ supb) {
    __shared__ float Ab[64][65];
    __shared__ float4 hs[64][32];
    int cc = blockIdx.x;
    int d = blockIdx.y, m = blockIdx.z;
    int dbase = d * 64, cb = cc * 128;
    int t = threadIdx.x;
    size_t bbase = (size_t)(m * N_DIA + d) * 4096;
#pragma unroll
    for (int q = 0; q < 16; q++) {
        int e = t + 256 * q;
        int i = e >> 6, j = e & 63;
        Ab[i][j] = blk[bbase + e] * dinv[m * NTOT + dbase + i] * dinv[m * NTOT + dbase + j];
    }
#pragma unroll
    for (int q = 0; q < 8; q++) {
        int f4 = t + 256 * q;
        int j = f4 >> 5, c4 = f4 & 31;
        hs[j][c4] = *(const float4*)(h + (size_t)(m * NTOT + dbase + j) * DD + cb + c4 * 4);
    }
    __syncthreads();
    int tx = t & 31, ty = t >> 5;
    float4 acc[8];
#pragma unroll
    for (int i = 0; i < 8; i++) acc[i] = make_float4(0.f, 0.f, 0.f, 0.f);
    for (int j = 0; j < 64; j++) {
        float4 b = hs[j][tx];
#pragma unroll
        for (int rr = 0; rr < 8; rr++) {
            float aw = Ab[ty * 8 + rr][j];
            acc[rr].x += aw * b.x; acc[rr].y += aw * b.y;
            acc[rr].z += aw * b.z; acc[rr].w += aw * b.w;
        }
    }
#pragma unroll
    for (int rr = 0; rr < 8; rr++) {
        int i = ty * 8 + rr;
        int gi = dbase + i;
        float dm = dinv[m * NTOT + gi];
#pragma unroll
        for (int n = 0; n < 3; n++) {
            if (n == m) continue;
            int p = m + n - 1;
            float cval = cross[p * NTOT + gi] * dm * dinv[n * NTOT + gi];
            float4 hv = *(const float4*)(h + (size_t)(n * NTOT + gi) * DD + cb + tx * 4);
            acc[rr].x += cval * hv.x; acc[rr].y += cval * hv.y;
            acc[rr].z += cval * hv.z; acc[rr].w += cval * hv.w;
        }
        size_t o = (size_t)(m * NTOT + gi) * DD + cb + tx * 4;
        float4 h0v = *(const float4*)(h0 + o);
        ushort4 w;
        w.x = f2bf(0.9f * acc[rr].x + 0.1f * h0v.x);
        w.y = f2bf(0.9f * acc[rr].y + 0.1f * h0v.y);
        w.z = f2bf(0.9f * acc[rr].z + 0.1f * h0v.z);
        w.w = f2bf(0.9f * acc[rr].w + 0.1f * h0v.w);
        *(ushort4*)(supb + o) = w;
    }
}

// ---------- K8: assemble output ----------
__global__ void k_out(const float* __restrict__ a, const float* __restrict__ v,
                      const float* __restrict__ xl, const float* __restrict__ h,
                      float* __restrict__ out) {
    int i = blockIdx.x, t = threadIdx.x;
#pragma unroll
    for (int q = 0; q < 3; q++) {
        int f4 = t + 256 * q;
        int c = f4 * 4;
        int m = c >> 10;
        int ccol = c & 1023;
        float4 val;
        if (ccol < 512) {
            const float* src = (m == 0) ? a : (m == 1) ? v : xl;
            val = *(const float4*)(src + (size_t)i * DD + ccol);
        } else {
            val = *(const float4*)(h + (size_t)(m * NTOT + i) * DD + (ccol - 512));
        }
        *(float4*)(out + (size_t)i * 3072 + c) = val;
    }
}

extern "C" void kernel_launch(void* const* d_in, const int* in_sizes, int n_in,
                              void* d_out, int out_size, void* d_ws, size_t ws_size,
                              hipStream_t stream) {
    (void)in_sizes; (void)n_in; (void)out_size; (void)ws_size;
    const float* a     = (const float*)d_in[0];
    const float* v     = (const float*)d_in[1];
    const float* l     = (const float*)d_in[2];
    const float* qmask = (const float*)d_in[3];
    const float* Wspk  = (const float*)d_in[5];
    const float* W0    = (const float*)d_in[6];
    const float* b0    = (const float*)d_in[7];
    const float* Wg    = (const float*)d_in[8];
    float* out = (float*)d_out;
    float* ws = (float*)d_ws;

    const size_t big = 3 * SEG;                         // 4,718,592 floats
    float* xl    = ws;                                  // SEG
    float* invn  = xl + SEG;                            // M3
    float* blk   = invn + M3;                           // 589,824
    float* cross = blk + (size_t)3 * N_DIA * 4096;      // M3
    float* dinvp = cross + M3;                          // M3
    unsigned short* Wt  = (unsigned short*)(dinvp + M3);     // 393,216 f
    unsigned short* xb  = (unsigned short*)((float*)Wt + 393216);  // 3*SEG us = 2,359,296 f
    unsigned short* supb = xb;                          // alias: xb dead after gemm0
    float* h  = (float*)(xb + 2 * big);                 // big floats (note: 3*SEG us = 1.5*big f)
    float* h0 = h + big;                                // big floats

    k_pre<<<NTOT, 64, 0, stream>>>(a, v, l, qmask, Wspk, xl, xb, invn, cross);
    k_wt <<<dim3(16, 16, 3), 256, 0, stream>>>(W0, Wg, Wt);
    k_gram_mfma<<<dim3(N_DIA, 3), 256, 0, stream>>>(xb, invn, cross, blk, dinvp);

    const float th1 = 0.40546510810816438f;  // log(1.5)
    const float th2 = 0.22314355131420976f;  // log(1.25)

    // h0 = relu(x @ W0 + b0)
    k_gemm_mfma<<<dim3(4, 72), 256, 0, stream>>>(xb, Wt, b0, xb, h0, 0.f, 0);
    // layer 1
    k_adjmul<<<dim3(4, N_DIA, 3), 256, 0, stream>>>(blk, cross, dinvp, h0, h0, supb);
    k_gemm_mfma<<<dim3(4, 72), 256, 0, stream>>>(supb, Wt + (size_t)DD * DD, b0, supb, h, th1, 1);
    // layer 2
    k_adjmul<<<dim3(4, N_DIA, 3), 256, 0, stream>>>(blk, cross, dinvp, h, h0, supb);
    k_gemm_mfma<<<dim3(4, 72), 256, 0, stream>>>(supb, Wt + (size_t)2 * DD * DD, b0, supb, h, th2, 1);

    k_out<<<NTOT, 256, 0, stream>>>(a, v, xl, h, out);
}

// Round 7
// 212.897 us; speedup vs baseline: 2.0112x; 1.0994x over previous
//
#include <hip/hip_runtime.h>
#include <math.h>

#define N_DIA 48
#define NTOT  3072     // N utterances
#define DD    512      // D == H
#define M3    9216     // 3N
#define SEG   ((size_t)NTOT * DD)

#define SCALE_F 0.99999f
#define PI_F    3.14159274101257324f

typedef __attribute__((ext_vector_type(8))) short frag8;
typedef __attribute__((ext_vector_type(4))) float f32x4;

__device__ __forceinline__ float ang_sim(float cs) {
    float cc = cs * SCALE_F;
    cc = fminf(fmaxf(cc, -SCALE_F), SCALE_F);
    return 1.0f - acosf(cc) / PI_F;
}
__device__ __forceinline__ unsigned short f2bf(float x) {
    union { float f; unsigned int u; } c; c.f = x;
    unsigned int r = c.u + 0x7fffu + ((c.u >> 16) & 1u);
    return (unsigned short)(r >> 16);
}
__device__ __forceinline__ float bf2f(unsigned short h) {
    union { unsigned int u; float f; } c; c.u = ((unsigned int)h) << 16;
    return c.f;
}
__device__ __forceinline__ void gload16(const unsigned short* g, unsigned short* s) {
    __builtin_amdgcn_global_load_lds(
        (const __attribute__((address_space(1))) unsigned int*)g,
        (__attribute__((address_space(3))) unsigned int*)s, 16, 0, 0);
}

// ---------- K_pre: out x-columns, bf16 casts, inverse norms, cross sims ----------
__global__ __launch_bounds__(64) void k_pre(
    const float* __restrict__ a, const float* __restrict__ v,
    const float* __restrict__ l, const float* __restrict__ qmask,
    const float* __restrict__ Wspk,
    float* __restrict__ out, unsigned short* __restrict__ xb,
    float* __restrict__ invn, float* __restrict__ cross)
{
    int i = blockIdx.x, t = threadIdx.x;   // 64 threads = 1 wave
    int pos = i & 63, dia = i >> 6;
    int qb = (pos * N_DIA + dia) * 2;
    float q0 = qmask[qb], q1 = qmask[qb + 1];
    int spk = (q0 >= q1) ? 0 : 1;
    const float4* av4 = (const float4*)(a + (size_t)i * DD);
    const float4* vv4 = (const float4*)(v + (size_t)i * DD);
    const float4* lv4 = (const float4*)(l + (size_t)i * DD);
    const float4* wv4 = (const float4*)(Wspk + (size_t)spk * DD);
    float* ob = out + (size_t)i * 3072;
    float saa = 0, svv = 0, sll = 0, sav = 0, sal = 0, svl = 0;
#pragma unroll
    for (int e = 0; e < 2; e++) {
        int idx = t * 2 + e;
        float4 xa = av4[idx], xv = vv4[idx], xd = lv4[idx], xw = wv4[idx];
        float4 xL = make_float4(xd.x + xw.x, xd.y + xw.y, xd.z + xw.z, xd.w + xw.w);
        // x-columns of the final output: a @ 0, v @ 1024, xl @ 2048
        *(float4*)(ob + idx * 4)        = xa;
        *(float4*)(ob + 1024 + idx * 4) = xv;
        *(float4*)(ob + 2048 + idx * 4) = xL;
        ushort4 ya, yv, yl;
        ya.x = f2bf(xa.x); ya.y = f2bf(xa.y); ya.z = f2bf(xa.z); ya.w = f2bf(xa.w);
        yv.x = f2bf(xv.x); yv.y = f2bf(xv.y); yv.z = f2bf(xv.z); yv.w = f2bf(xv.w);
        yl.x = f2bf(xL.x); yl.y = f2bf(xL.y); yl.z = f2bf(xL.z); yl.w = f2bf(xL.w);
        *(ushort4*)(xb + (size_t)i * DD + idx * 4) = ya;
        *(ushort4*)(xb + SEG + (size_t)i * DD + idx * 4) = yv;
        *(ushort4*)(xb + 2 * SEG + (size_t)i * DD + idx * 4) = yl;
        saa += xa.x * xa.x + xa.y * xa.y + xa.z * xa.z + xa.w * xa.w;
        svv += xv.x * xv.x + xv.y * xv.y + xv.z * xv.z + xv.w * xv.w;
        sll += xL.x * xL.x + xL.y * xL.y + xL.z * xL.z + xL.w * xL.w;
        sav += xa.x * xv.x + xa.y * xv.y + xa.z * xv.z + xa.w * xv.w;
        sal += xa.x * xL.x + xa.y * xL.y + xa.z * xL.z + xa.w * xL.w;
        svl += xv.x * xL.x + xv.y * xL.y + xv.z * xL.z + xv.w * xL.w;
    }
#pragma unroll
    for (int off = 32; off; off >>= 1) {
        saa += __shfl_down(saa, off, 64);
        svv += __shfl_down(svv, off, 64);
        sll += __shfl_down(sll, off, 64);
        sav += __shfl_down(sav, off, 64);
        sal += __shfl_down(sal, off, 64);
        svl += __shfl_down(svl, off, 64);
    }
    if (t == 0) {
        float ina = 1.0f / sqrtf(saa);
        float inv_ = 1.0f / sqrtf(svv);
        float inl = 1.0f / sqrtf(sll);
        invn[i] = ina; invn[NTOT + i] = inv_; invn[2 * NTOT + i] = inl;
        cross[i]            = ang_sim(sav * ina * inv_);
        cross[NTOT + i]     = ang_sim(sal * ina * inl);
        cross[2 * NTOT + i] = ang_sim(svl * inv_ * inl);
    }
}

// ---------- gram (MFMA) + fused dinv ----------
__global__ __launch_bounds__(256) void k_gram_mfma(
    const unsigned short* __restrict__ xb, const float* __restrict__ invn,
    const float* __restrict__ cross, float* __restrict__ blk,
    float* __restrict__ dinv)
{
    __shared__ __align__(16) unsigned short Xs[16 * 2048];   // 64 KB
    int d = blockIdx.x, m = blockIdx.y;
    int t = threadIdx.x;
    int lane = t & 63, wv = t >> 6;
    int mrow = m * NTOT + d * 64;
    const unsigned short* src = xb + (size_t)mrow * DD;
#pragma unroll
    for (int c = 0; c < 16; c++) {
        gload16(src + (size_t)(t >> 2) * DD + c * 32 + (t & 3) * 8,
                &Xs[c * 2048 + wv * 512]);
    }
    __syncthreads();

    int rsel = lane & 15, quad = lane >> 4;
    f32x4 acc[4];
#pragma unroll
    for (int j = 0; j < 4; j++) acc[j] = (f32x4){0.f, 0.f, 0.f, 0.f};
#pragma unroll
    for (int c = 0; c < 16; c++) {
        const unsigned short* base = &Xs[c * 2048];
        frag8 bf[4];
#pragma unroll
        for (int j = 0; j < 4; j++)
            bf[j] = *(const frag8*)&base[(j * 16 + rsel) * 32 + quad * 8];
        frag8 af = *(const frag8*)&base[(wv * 16 + rsel) * 32 + quad * 8];
#pragma unroll
        for (int j = 0; j < 4; j++)
            acc[j] = __builtin_amdgcn_mfma_f32_16x16x32_bf16(af, bf[j], acc[j], 0, 0, 0);
    }

    size_t bbase = (size_t)(m * N_DIA + d) * 4096;
    int rowl0 = wv * 16 + quad * 4;
    float ir[4], rs[4] = {0.f, 0.f, 0.f, 0.f};
#pragma unroll
    for (int r = 0; r < 4; r++) ir[r] = invn[mrow + rowl0 + r];
#pragma unroll
    for (int j = 0; j < 4; j++) {
        int coll = j * 16 + rsel;
        float ic = invn[mrow + coll];
#pragma unroll
        for (int r = 0; r < 4; r++) {
            float sim = ang_sim(acc[j][r] * ir[r] * ic);
            blk[bbase + (size_t)(rowl0 + r) * 64 + coll] = sim;
            rs[r] += sim;
        }
    }
#pragma unroll
    for (int off = 8; off; off >>= 1)
#pragma unroll
        for (int r = 0; r < 4; r++) rs[r] += __shfl_down(rs[r], off, 16);
    if (rsel == 0) {
#pragma unroll
        for (int r = 0; r < 4; r++) {
            int gi = d * 64 + rowl0 + r;
            float c1, c2;
            if (m == 0)      { c1 = cross[gi];        c2 = cross[NTOT + gi]; }
            else if (m == 1) { c1 = cross[gi];        c2 = cross[2 * NTOT + gi]; }
            else             { c1 = cross[NTOT + gi]; c2 = cross[2 * NTOT + gi]; }
            dinv[m * NTOT + gi] = 1.0f / sqrtf(rs[r] + c1 + c2);
        }
    }
}

// ---------- prep: W -> bf16, transposed to [n][k] ----------
__global__ void k_wt(const float* __restrict__ W0, const float* __restrict__ Wg,
                     unsigned short* __restrict__ Wt) {
    __shared__ float tile[32][33];
    int bx = blockIdx.x, by = blockIdx.y, mm = blockIdx.z;
    const float* W = (mm == 0) ? W0 : Wg + (size_t)(mm - 1) * DD * DD;
    int t = threadIdx.x;
    int tx = t & 31, ty = t >> 5;
#pragma unroll
    for (int q = 0; q < 4; q++) {
        int k = by * 32 + ty + q * 8;
        tile[ty + q * 8][tx] = W[(size_t)k * DD + bx * 32 + tx];
    }
    __syncthreads();
#pragma unroll
    for (int q = 0; q < 4; q++) {
        int n = bx * 32 + ty + q * 8;
        Wt[(size_t)mm * DD * DD + (size_t)n * DD + by * 32 + tx] = f2bf(tile[tx][ty + q * 8]);
    }
}

// ---------- GEMM: 64(M) x 128(N) tile, LDS + gload16, bf16 MFMA ----------
// mode 0: relu(acc + bias[col]) -> outp[row*512+col]
// mode 1: relu(theta*acc + (1-theta)*bf2f(resid)) -> outp[row*512+col]
// mode 2: same blend, but write to final out layout outp[i*3072 + m*1024 + 512 + col]
__global__ __launch_bounds__(256) void k_gemm_mfma(
    const unsigned short* __restrict__ A, const unsigned short* __restrict__ Wt,
    const float* __restrict__ bias, const unsigned short* __restrict__ resid,
    float* __restrict__ outp, float theta, int mode)
{
    __shared__ __align__(16) unsigned short As[64 * 32];    // 4 KB
    __shared__ __align__(16) unsigned short Bs[128 * 32];   // 8 KB
    int t = threadIdx.x;
    int lane = t & 63, wv = t >> 6;
    int mbase = blockIdx.y * 64, nbase = blockIdx.x * 128;
    int srow = lane >> 2;          // 0..15
    int scol = (lane & 3) * 8;     // ushort offset within 32-wide K slice
    int rsel = lane & 15, quad = lane >> 4;

    // wave wv stages A rows wv*16..+15 and B rows (cols of W) wv*32..+31
    const unsigned short* Ag  = A  + (size_t)(mbase + wv * 16 + srow) * DD + scol;
    const unsigned short* Bg0 = Wt + (size_t)(nbase + wv * 32 + srow) * DD + scol;
    const unsigned short* Bg1 = Wt + (size_t)(nbase + wv * 32 + 16 + srow) * DD + scol;
    unsigned short* Asl  = &As[wv * 512];
    unsigned short* Bsl0 = &Bs[wv * 1024];
    unsigned short* Bsl1 = &Bs[wv * 1024 + 512];

    f32x4 acc[8];
#pragma unroll
    for (int i = 0; i < 8; i++) acc[i] = (f32x4){0.f, 0.f, 0.f, 0.f};

    for (int kt = 0; kt < DD; kt += 32) {
        __syncthreads();
        gload16(Ag + kt, Asl);
        gload16(Bg0 + kt, Bsl0);
        gload16(Bg1 + kt, Bsl1);
        __syncthreads();
        frag8 af[4], bfr[2];
#pragma unroll
        for (int i = 0; i < 4; i++)
            af[i] = *(const frag8*)&As[(i * 16 + rsel) * 32 + quad * 8];
#pragma unroll
        for (int j = 0; j < 2; j++)
            bfr[j] = *(const frag8*)&Bs[(wv * 32 + j * 16 + rsel) * 32 + quad * 8];
#pragma unroll
        for (int i = 0; i < 4; i++)
#pragma unroll
            for (int j = 0; j < 2; j++)
                acc[i * 2 + j] = __builtin_amdgcn_mfma_f32_16x16x32_bf16(
                    af[i], bfr[j], acc[i * 2 + j], 0, 0, 0);
    }

    float omt = 1.0f - theta;
    int mq = mbase / NTOT;                   // modality (uniform per block)
    int iu0 = mbase - mq * NTOT;             // utterance row base
#pragma unroll
    for (int i = 0; i < 4; i++)
#pragma unroll
        for (int j = 0; j < 2; j++) {
            int col = nbase + wv * 32 + j * 16 + rsel;
            int rowl = i * 16 + quad * 4;    // local row base
            f32x4 r = acc[i * 2 + j];
#pragma unroll
            for (int rr = 0; rr < 4; rr++) {
                float vv = r[rr];
                int row = mbase + rowl + rr;
                size_t o = (size_t)row * DD + col;
                if (mode == 0) vv += bias[col];
                else vv = theta * vv + omt * bf2f(resid[o]);
                vv = fmaxf(vv, 0.f);
                if (mode == 2)
                    outp[(size_t)(iu0 + rowl + rr) * 3072 + mq * 1024 + 512 + col] = vv;
                else
                    outp[o] = vv;
            }
        }
}

// ---------- adjmul: sparse adj @ h (fp32 in) -> supb bf16 ----------
__global__ __launch_bounds__(256) void k_adjmul(
    const float* __restrict__ blk, const float* __restrict__ cross,
    const float* __restrict__ dinv, const float* __restrict__ h,
    const float* __restrict__ h0, unsigned short* __restrict__ supb) {
    __shared__ float Ab[64][65];
    __shared__ float4 hs[64][32];
    int cc = blockIdx.x;
    int d = blockIdx.y, m = blockIdx.z;
    int dbase = d * 64, cb = cc * 128;
    int t = threadIdx.x;
    size_t bbase = (size_t)(m * N_DIA + d) * 4096;
#pragma unroll
    for (int q = 0; q < 16; q++) {
        int e = t + 256 * q;
        int i = e >> 6, j = e & 63;
        Ab[i][j] = blk[bbase + e] * dinv[m * NTOT + dbase + i] * dinv[m * NTOT + dbase + j];
    }
#pragma unroll
    for (int q = 0; q < 8; q++) {
        int f4 = t + 256 * q;
        int j = f4 >> 5, c4 = f4 & 31;
        hs[j][c4] = *(const float4*)(h + (size_t)(m * NTOT + dbase + j) * DD + cb + c4 * 4);
    }
    __syncthreads();
    int tx = t & 31, ty = t >> 5;
    float4 acc[8];
#pragma unroll
    for (int i = 0; i < 8; i++) acc[i] = make_float4(0.f, 0.f, 0.f, 0.f);
    for (int j = 0; j < 64; j++) {
        float4 b = hs[j][tx];
#pragma unroll
        for (int rr = 0; rr < 8; rr++) {
            float aw = Ab[ty * 8 + rr][j];
            acc[rr].x += aw * b.x; acc[rr].y += aw * b.y;
            acc[rr].z += aw * b.z; acc[rr].w += aw * b.w;
        }
    }
#pragma unroll
    for (int rr = 0; rr < 8; rr++) {
        int i = ty * 8 + rr;
        int gi = dbase + i;
        float dm = dinv[m * NTOT + gi];
#pragma unroll
        for (int n = 0; n < 3; n++) {
            if (n == m) continue;
            int p = m + n - 1;
            float cval = cross[p * NTOT + gi] * dm * dinv[n * NTOT + gi];
            float4 hv = *(const float4*)(h + (size_t)(n * NTOT + gi) * DD + cb + tx * 4);
            acc[rr].x += cval * hv.x; acc[rr].y += cval * hv.y;
            acc[rr].z += cval * hv.z; acc[rr].w += cval * hv.w;
        }
        size_t o = (size_t)(m * NTOT + gi) * DD + cb + tx * 4;
        float4 h0v = *(const float4*)(h0 + o);
        ushort4 w;
        w.x = f2bf(0.9f * acc[rr].x + 0.1f * h0v.x);
        w.y = f2bf(0.9f * acc[rr].y + 0.1f * h0v.y);
        w.z = f2bf(0.9f * acc[rr].z + 0.1f * h0v.z);
        w.w = f2bf(0.9f * acc[rr].w + 0.1f * h0v.w);
        *(ushort4*)(supb + o) = w;
    }
}

extern "C" void kernel_launch(void* const* d_in, const int* in_sizes, int n_in,
                              void* d_out, int out_size, void* d_ws, size_t ws_size,
                              hipStream_t stream) {
    (void)in_sizes; (void)n_in; (void)out_size; (void)ws_size;
    const float* a     = (const float*)d_in[0];
    const float* v     = (const float*)d_in[1];
    const float* l     = (const float*)d_in[2];
    const float* qmask = (const float*)d_in[3];
    const float* Wspk  = (const float*)d_in[5];
    const float* W0    = (const float*)d_in[6];
    const float* b0    = (const float*)d_in[7];
    const float* Wg    = (const float*)d_in[8];
    float* out = (float*)d_out;
    float* ws = (float*)d_ws;

    const size_t big = 3 * SEG;                         // 4,718,592 floats
    float* invn  = ws;                                  // M3
    float* blk   = invn + M3;                           // 589,824
    float* cross = blk + (size_t)3 * N_DIA * 4096;      // M3
    float* dinvp = cross + M3;                          // M3
    unsigned short* Wt  = (unsigned short*)(dinvp + M3);     // 786,432 us = 393,216 f
    unsigned short* xb  = (unsigned short*)((float*)Wt + 393216);  // 3*SEG us
    unsigned short* supb = xb;                          // alias: xb dead after gemm0
    float* h0 = (float*)(xb + big);                     // big floats (xb is 3*SEG us = 1.5*big f... region sized below)
    float* h  = h0 + big;                               // big floats

    k_pre<<<NTOT, 64, 0, stream>>>(a, v, l, qmask, Wspk, out, xb, invn, cross);
    k_wt <<<dim3(16, 16, 3), 256, 0, stream>>>(W0, Wg, Wt);
    k_gram_mfma<<<dim3(N_DIA, 3), 256, 0, stream>>>(xb, invn, cross, blk, dinvp);

    const float th1 = 0.40546510810816438f;  // log(1.5)
    const float th2 = 0.22314355131420976f;  // log(1.25)

    // h0 = relu(x @ W0 + b0)
    k_gemm_mfma<<<dim3(4, 144), 256, 0, stream>>>(xb, Wt, b0, xb, h0, 0.f, 0);
    // layer 1
    k_adjmul<<<dim3(4, N_DIA, 3), 256, 0, stream>>>(blk, cross, dinvp, h0, h0, supb);
    k_gemm_mfma<<<dim3(4, 144), 256, 0, stream>>>(supb, Wt + (size_t)DD * DD, b0, supb, h, th1, 1);
    // layer 2
    k_adjmul<<<dim3(4, N_DIA, 3), 256, 0, stream>>>(blk, cross, dinvp, h, h0, supb);
    k_gemm_mfma<<<dim3(4, 144), 256, 0, stream>>>(supb, Wt + (size_t)2 * DD * DD, b0, supb, out, th2, 2);
}

// Round 9
// 202.565 us; speedup vs baseline: 2.1137x; 1.0510x over previous
//
#include <hip/hip_runtime.h>
#include <math.h>

#define N_DIA 48
#define NTOT  3072     // N utterances
#define DD    512      // D == H
#define M3    9216     // 3N
#define SEG   ((size_t)NTOT * DD)

#define SCALE_F 0.99999f
#define PI_F    3.14159274101257324f

typedef __attribute__((ext_vector_type(8))) short frag8;
typedef __attribute__((ext_vector_type(4))) float f32x4;

__device__ __forceinline__ float ang_sim(float cs) {
    float cc = cs * SCALE_F;
    cc = fminf(fmaxf(cc, -SCALE_F), SCALE_F);
    return 1.0f - acosf(cc) / PI_F;
}
__device__ __forceinline__ unsigned short f2bf(float x) {
    union { float f; unsigned int u; } c; c.f = x;
    unsigned int r = c.u + 0x7fffu + ((c.u >> 16) & 1u);
    return (unsigned short)(r >> 16);
}
__device__ __forceinline__ float bf2f(unsigned short h) {
    union { unsigned int u; float f; } c; c.u = ((unsigned int)h) << 16;
    return c.f;
}
__device__ __forceinline__ void gload16(const unsigned short* g, unsigned short* s) {
    __builtin_amdgcn_global_load_lds(
        (const __attribute__((address_space(1))) unsigned int*)g,
        (__attribute__((address_space(3))) unsigned int*)s, 16, 0, 0);
}

// ---------- K_pre: out x-columns, bf16 casts, inverse norms, cross sims ----------
__global__ __launch_bounds__(64) void k_pre(
    const float* __restrict__ a, const float* __restrict__ v,
    const float* __restrict__ l, const float* __restrict__ qmask,
    const float* __restrict__ Wspk,
    float* __restrict__ out, unsigned short* __restrict__ xb,
    float* __restrict__ invn, float* __restrict__ cross)
{
    int i = blockIdx.x, t = threadIdx.x;   // 64 threads = 1 wave
    int pos = i & 63, dia = i >> 6;
    int qb = (pos * N_DIA + dia) * 2;
    float q0 = qmask[qb], q1 = qmask[qb + 1];
    int spk = (q0 >= q1) ? 0 : 1;
    const float4* av4 = (const float4*)(a + (size_t)i * DD);
    const float4* vv4 = (const float4*)(v + (size_t)i * DD);
    const float4* lv4 = (const float4*)(l + (size_t)i * DD);
    const float4* wv4 = (const float4*)(Wspk + (size_t)spk * DD);
    float* ob = out + (size_t)i * 3072;
    float saa = 0, svv = 0, sll = 0, sav = 0, sal = 0, svl = 0;
#pragma unroll
    for (int e = 0; e < 2; e++) {
        int idx = t * 2 + e;
        float4 xa = av4[idx], xv = vv4[idx], xd = lv4[idx], xw = wv4[idx];
        float4 xL = make_float4(xd.x + xw.x, xd.y + xw.y, xd.z + xw.z, xd.w + xw.w);
        *(float4*)(ob + idx * 4)        = xa;
        *(float4*)(ob + 1024 + idx * 4) = xv;
        *(float4*)(ob + 2048 + idx * 4) = xL;
        ushort4 ya, yv, yl;
        ya.x = f2bf(xa.x); ya.y = f2bf(xa.y); ya.z = f2bf(xa.z); ya.w = f2bf(xa.w);
        yv.x = f2bf(xv.x); yv.y = f2bf(xv.y); yv.z = f2bf(xv.z); yv.w = f2bf(xv.w);
        yl.x = f2bf(xL.x); yl.y = f2bf(xL.y); yl.z = f2bf(xL.z); yl.w = f2bf(xL.w);
        *(ushort4*)(xb + (size_t)i * DD + idx * 4) = ya;
        *(ushort4*)(xb + SEG + (size_t)i * DD + idx * 4) = yv;
        *(ushort4*)(xb + 2 * SEG + (size_t)i * DD + idx * 4) = yl;
        saa += xa.x * xa.x + xa.y * xa.y + xa.z * xa.z + xa.w * xa.w;
        svv += xv.x * xv.x + xv.y * xv.y + xv.z * xv.z + xv.w * xv.w;
        sll += xL.x * xL.x + xL.y * xL.y + xL.z * xL.z + xL.w * xL.w;
        sav += xa.x * xv.x + xa.y * xv.y + xa.z * xv.z + xa.w * xv.w;
        sal += xa.x * xL.x + xa.y * xL.y + xa.z * xL.z + xa.w * xL.w;
        svl += xv.x * xL.x + xv.y * xL.y + xv.z * xL.z + xv.w * xL.w;
    }
#pragma unroll
    for (int off = 32; off; off >>= 1) {
        saa += __shfl_down(saa, off, 64);
        svv += __shfl_down(svv, off, 64);
        sll += __shfl_down(sll, off, 64);
        sav += __shfl_down(sav, off, 64);
        sal += __shfl_down(sal, off, 64);
        svl += __shfl_down(svl, off, 64);
    }
    if (t == 0) {
        float ina = 1.0f / sqrtf(saa);
        float inv_ = 1.0f / sqrtf(svv);
        float inl = 1.0f / sqrtf(sll);
        invn[i] = ina; invn[NTOT + i] = inv_; invn[2 * NTOT + i] = inl;
        cross[i]            = ang_sim(sav * ina * inv_);
        cross[NTOT + i]     = ang_sim(sal * ina * inl);
        cross[2 * NTOT + i] = ang_sim(svl * inv_ * inl);
    }
}

// ---------- gram (MFMA) + fused dinv ----------
__global__ __launch_bounds__(256) void k_gram_mfma(
    const unsigned short* __restrict__ xb, const float* __restrict__ invn,
    const float* __restrict__ cross, float* __restrict__ blk,
    float* __restrict__ dinv)
{
    __shared__ __align__(16) unsigned short Xs[16 * 2048];   // 64 KB
    int d = blockIdx.x, m = blockIdx.y;
    int t = threadIdx.x;
    int lane = t & 63, wv = t >> 6;
    int mrow = m * NTOT + d * 64;
    const unsigned short* src = xb + (size_t)mrow * DD;
#pragma unroll
    for (int c = 0; c < 16; c++) {
        gload16(src + (size_t)(t >> 2) * DD + c * 32 + (t & 3) * 8,
                &Xs[c * 2048 + wv * 512]);
    }
    __syncthreads();

    int rsel = lane & 15, quad = lane >> 4;
    f32x4 acc[4];
#pragma unroll
    for (int j = 0; j < 4; j++) acc[j] = (f32x4){0.f, 0.f, 0.f, 0.f};
#pragma unroll
    for (int c = 0; c < 16; c++) {
        const unsigned short* base = &Xs[c * 2048];
        frag8 bf[4];
#pragma unroll
        for (int j = 0; j < 4; j++)
            bf[j] = *(const frag8*)&base[(j * 16 + rsel) * 32 + quad * 8];
        frag8 af = *(const frag8*)&base[(wv * 16 + rsel) * 32 + quad * 8];
#pragma unroll
        for (int j = 0; j < 4; j++)
            acc[j] = __builtin_amdgcn_mfma_f32_16x16x32_bf16(af, bf[j], acc[j], 0, 0, 0);
    }

    size_t bbase = (size_t)(m * N_DIA + d) * 4096;
    int rowl0 = wv * 16 + quad * 4;
    float ir[4], rs[4] = {0.f, 0.f, 0.f, 0.f};
#pragma unroll
    for (int r = 0; r < 4; r++) ir[r] = invn[mrow + rowl0 + r];
#pragma unroll
    for (int j = 0; j < 4; j++) {
        int coll = j * 16 + rsel;
        float ic = invn[mrow + coll];
#pragma unroll
        for (int r = 0; r < 4; r++) {
            float sim = ang_sim(acc[j][r] * ir[r] * ic);
            blk[bbase + (size_t)(rowl0 + r) * 64 + coll] = sim;
            rs[r] += sim;
        }
    }
#pragma unroll
    for (int off = 8; off; off >>= 1)
#pragma unroll
        for (int r = 0; r < 4; r++) rs[r] += __shfl_down(rs[r], off, 16);
    if (rsel == 0) {
#pragma unroll
        for (int r = 0; r < 4; r++) {
            int gi = d * 64 + rowl0 + r;
            float c1, c2;
            if (m == 0)      { c1 = cross[gi];        c2 = cross[NTOT + gi]; }
            else if (m == 1) { c1 = cross[gi];        c2 = cross[2 * NTOT + gi]; }
            else             { c1 = cross[NTOT + gi]; c2 = cross[2 * NTOT + gi]; }
            dinv[m * NTOT + gi] = 1.0f / sqrtf(rs[r] + c1 + c2);
        }
    }
}

// ---------- prep: W -> bf16, transposed to [n][k] ----------
__global__ void k_wt(const float* __restrict__ W0, const float* __restrict__ Wg,
                     unsigned short* __restrict__ Wt) {
    __shared__ float tile[32][33];
    int bx = blockIdx.x, by = blockIdx.y, mm = blockIdx.z;
    const float* W = (mm == 0) ? W0 : Wg + (size_t)(mm - 1) * DD * DD;
    int t = threadIdx.x;
    int tx = t & 31, ty = t >> 5;
#pragma unroll
    for (int q = 0; q < 4; q++) {
        int k = by * 32 + ty + q * 8;
        tile[ty + q * 8][tx] = W[(size_t)k * DD + bx * 32 + tx];
    }
    __syncthreads();
#pragma unroll
    for (int q = 0; q < 4; q++) {
        int n = bx * 32 + ty + q * 8;
        Wt[(size_t)mm * DD * DD + (size_t)n * DD + by * 32 + tx] = f2bf(tile[tx][ty + q * 8]);
    }
}

// ---------- GEMM: 64(M) x 128(N) tile, LDS + gload16, bf16 MFMA ----------
// mode 0: relu(acc + bias[col])            -> hT bf16 + hrow bf16
// mode 1: relu(theta*acc+(1-theta)*resid)  -> hT bf16 + hrow bf16
// mode 2: same blend                       -> outF fp32 at i*3072 + m*1024 + 512 + col
__global__ __launch_bounds__(256) void k_gemm_mfma(
    const unsigned short* __restrict__ A, const unsigned short* __restrict__ Wt,
    const float* __restrict__ bias, const unsigned short* __restrict__ resid,
    unsigned short* __restrict__ outT, unsigned short* __restrict__ outR,
    float* __restrict__ outF, float theta, int mode)
{
    __shared__ __align__(16) unsigned short As[64 * 32];    // 4 KB
    __shared__ __align__(16) unsigned short Bs[128 * 32];   // 8 KB
    int t = threadIdx.x;
    int lane = t & 63, wv = t >> 6;
    int mbase = blockIdx.y * 64, nbase = blockIdx.x * 128;
    int srow = lane >> 2;
    int scol = (lane & 3) * 8;
    int rsel = lane & 15, quad = lane >> 4;

    const unsigned short* Ag  = A  + (size_t)(mbase + wv * 16 + srow) * DD + scol;
    const unsigned short* Bg0 = Wt + (size_t)(nbase + wv * 32 + srow) * DD + scol;
    const unsigned short* Bg1 = Wt + (size_t)(nbase + wv * 32 + 16 + srow) * DD + scol;
    unsigned short* Asl  = &As[wv * 512];
    unsigned short* Bsl0 = &Bs[wv * 1024];
    unsigned short* Bsl1 = &Bs[wv * 1024 + 512];

    f32x4 acc[8];
#pragma unroll
    for (int i = 0; i < 8; i++) acc[i] = (f32x4){0.f, 0.f, 0.f, 0.f};

    for (int kt = 0; kt < DD; kt += 32) {
        __syncthreads();
        gload16(Ag + kt, Asl);
        gload16(Bg0 + kt, Bsl0);
        gload16(Bg1 + kt, Bsl1);
        __syncthreads();
        frag8 af[4], bfr[2];
#pragma unroll
        for (int i = 0; i < 4; i++)
            af[i] = *(const frag8*)&As[(i * 16 + rsel) * 32 + quad * 8];
#pragma unroll
        for (int j = 0; j < 2; j++)
            bfr[j] = *(const frag8*)&Bs[(wv * 32 + j * 16 + rsel) * 32 + quad * 8];
#pragma unroll
        for (int i = 0; i < 4; i++)
#pragma unroll
            for (int j = 0; j < 2; j++)
                acc[i * 2 + j] = __builtin_amdgcn_mfma_f32_16x16x32_bf16(
                    af[i], bfr[j], acc[i * 2 + j], 0, 0, 0);
    }

    float omt = 1.0f - theta;
    int mq = mbase / NTOT;
    int iu0 = mbase - mq * NTOT;
#pragma unroll
    for (int i = 0; i < 4; i++)
#pragma unroll
        for (int j = 0; j < 2; j++) {
            int col = nbase + wv * 32 + j * 16 + rsel;
            int rowl = i * 16 + quad * 4;             // local row base (0..63)
            int rowb = mbase + rowl;                  // global row base
            f32x4 r = acc[i * 2 + j];
            float vv[4];
#pragma unroll
            for (int rr = 0; rr < 4; rr++) {
                float x = r[rr];
                if (mode == 0) x += bias[col];
                else x = theta * x + omt * bf2f(resid[(size_t)(rowb + rr) * DD + col]);
                vv[rr] = fmaxf(x, 0.f);
            }
            if (mode == 2) {
#pragma unroll
                for (int rr = 0; rr < 4; rr++)
                    outF[(size_t)(iu0 + rowl + rr) * 3072 + mq * 1024 + 512 + col] = vv[rr];
            } else {
                ushort4 w4;
                w4.x = f2bf(vv[0]); w4.y = f2bf(vv[1]);
                w4.z = f2bf(vv[2]); w4.w = f2bf(vv[3]);
                *(ushort4*)(outT + (size_t)col * M3 + rowb) = w4;   // hT[col][row..row+3]
#pragma unroll
                for (int rr = 0; rr < 4; rr++)
                    outR[(size_t)(rowb + rr) * DD + col] = f2bf(vv[rr]);
            }
        }
}

// ---------- adjmul via MFMA: sup = bf16(0.9*(Ad@h + cross terms) + 0.1*h0) ----------
// A-op = hT rows (k=j contiguous), B-op = Ad rows (symmetric), out = sup row-major.
__global__ __launch_bounds__(256) void k_adjmul_mfma(
    const float* __restrict__ blk, const float* __restrict__ cross,
    const float* __restrict__ dinv,
    const unsigned short* __restrict__ hT, const unsigned short* __restrict__ hrow,
    const unsigned short* __restrict__ h0row, unsigned short* __restrict__ supb)
{
    __shared__ __align__(16) unsigned short AdL[64 * 72];    //  9 KB, pitch 72
    __shared__ __align__(16) unsigned short hTL[256 * 72];   // 36 KB, pitch 72
    __shared__ float dv[64];
    int cc = blockIdx.x, d = blockIdx.y, m = blockIdx.z;
    int t = threadIdx.x;
    int lane = t & 63, wv = t >> 6;
    int dbase = d * 64, cbase = cc * 256;
    int rsel = lane & 15, quad = lane >> 4;

    if (t < 64) dv[t] = dinv[m * NTOT + dbase + t];
    __syncthreads();

    // stage Ad = dinv_i * blk * dinv_j  (bf16, row-major, pitch 72)
    size_t bbase = (size_t)(m * N_DIA + d) * 4096;
#pragma unroll
    for (int q = 0; q < 4; q++) {
        int e4 = t + 256 * q;              // 0..1023
        int i = e4 >> 4, j4 = e4 & 15;
        float4 w = *(const float4*)(blk + bbase + (size_t)i * 64 + j4 * 4);
        float di = dv[i];
        ushort4 o;
        o.x = f2bf(w.x * di * dv[j4 * 4 + 0]);
        o.y = f2bf(w.y * di * dv[j4 * 4 + 1]);
        o.z = f2bf(w.z * di * dv[j4 * 4 + 2]);
        o.w = f2bf(w.w * di * dv[j4 * 4 + 3]);
        *(ushort4*)&AdL[i * 72 + j4 * 4] = o;
    }
    // stage hT slice: 256 c-rows x 64 j  (bf16, pitch 72) — 2048 uint4 loads
#pragma unroll
    for (int p = 0; p < 8; p++) {
        int e = t + 256 * p;               // 0..2047
        int cl = e >> 3;                   // 0..255
        int jo = (e & 7) * 8;              // 0..56
        uint4 w = *(const uint4*)(hT + (size_t)(cbase + cl) * M3 + m * NTOT + dbase + jo);
        *(uint4*)&hTL[cl * 72 + jo] = w;
    }
    __syncthreads();

    f32x4 acc[16];
#pragma unroll
    for (int i = 0; i < 16; i++) acc[i] = (f32x4){0.f, 0.f, 0.f, 0.f};
#pragma unroll
    for (int kk = 0; kk < 2; kk++) {
        frag8 bfr[4];
#pragma unroll
        for (int it = 0; it < 4; it++)
            bfr[it] = *(const frag8*)&AdL[(it * 16 + rsel) * 72 + kk * 32 + quad * 8];
#pragma unroll
        for (int jc = 0; jc < 4; jc++) {
            frag8 af = *(const frag8*)&hTL[(wv * 64 + jc * 16 + rsel) * 72 + kk * 32 + quad * 8];
#pragma unroll
            for (int it = 0; it < 4; it++)
                acc[jc * 4 + it] = __builtin_amdgcn_mfma_f32_16x16x32_bf16(
                    af, bfr[it], acc[jc * 4 + it], 0, 0, 0);
        }
    }

    // epilogue: D[m=c][n=i] -> lane holds i=rsel fixed, regs = 4 consecutive c
    int n1, n2, p1, p2;
    if (m == 0)      { n1 = 1; n2 = 2; p1 = 0; p2 = 1; }
    else if (m == 1) { n1 = 0; n2 = 2; p1 = 0; p2 = 2; }
    else             { n1 = 0; n2 = 1; p1 = 1; p2 = 2; }
#pragma unroll
    for (int it = 0; it < 4; it++) {
        int il = it * 16 + rsel;
        int gi = dbase + il;
        float dm = dv[il];
        float cv1 = cross[p1 * NTOT + gi] * dm * dinv[n1 * NTOT + gi];
        float cv2 = cross[p2 * NTOT + gi] * dm * dinv[n2 * NTOT + gi];
        size_t r1 = (size_t)(n1 * NTOT + gi) * DD;
        size_t r2 = (size_t)(n2 * NTOT + gi) * DD;
        size_t r0 = (size_t)(m * NTOT + gi) * DD;
#pragma unroll
        for (int jc = 0; jc < 4; jc++) {
            int cb = cbase + wv * 64 + jc * 16 + quad * 4;
            ushort4 u1 = *(const ushort4*)(hrow + r1 + cb);
            ushort4 u2 = *(const ushort4*)(hrow + r2 + cb);
            ushort4 u0 = *(const ushort4*)(h0row + r0 + cb);
            f32x4 aa = acc[jc * 4 + it];
            ushort4 w;
            w.x = f2bf(0.9f * (aa[0] + cv1 * bf2f(u1.x) + cv2 * bf2f(u2.x)) + 0.1f * bf2f(u0.x));
            w.y = f2bf(0.9f * (aa[1] + cv1 * bf2f(u1.y) + cv2 * bf2f(u2.y)) + 0.1f * bf2f(u0.y));
            w.z = f2bf(0.9f * (aa[2] + cv1 * bf2f(u1.z) + cv2 * bf2f(u2.z)) + 0.1f * bf2f(u0.z));
            w.w = f2bf(0.9f * (aa[3] + cv1 * bf2f(u1.w) + cv2 * bf2f(u2.w)) + 0.1f * bf2f(u0.w));
            *(ushort4*)(supb + r0 + cb) = w;
        }
    }
}

extern "C" void kernel_launch(void* const* d_in, const int* in_sizes, int n_in,
                              void* d_out, int out_size, void* d_ws, size_t ws_size,
                              hipStream_t stream) {
    (void)in_sizes; (void)n_in; (void)out_size; (void)ws_size;
    const float* a     = (const float*)d_in[0];
    const float* v     = (const float*)d_in[1];
    const float* l     = (const float*)d_in[2];
    const float* qmask = (const float*)d_in[3];
    const float* Wspk  = (const float*)d_in[5];
    const float* W0    = (const float*)d_in[6];
    const float* b0    = (const float*)d_in[7];
    const float* Wg    = (const float*)d_in[8];
    float* out = (float*)d_out;
    float* ws = (float*)d_ws;

    float* invn  = ws;                                  // M3
    float* blk   = invn + M3;                           // 589,824
    float* cross = blk + (size_t)3 * N_DIA * 4096;      // M3
    float* dinvp = cross + M3;                          // M3
    unsigned short* Wt  = (unsigned short*)(dinvp + M3);   // 786,432 us
    unsigned short* xb  = Wt + (size_t)3 * DD * DD;        // 3*SEG us
    unsigned short* supb = xb;                             // alias: xb dead after gemm0
    unsigned short* h0T = xb + 3 * SEG;                    // 3*SEG us
    unsigned short* h0r = h0T + 3 * SEG;                   // 3*SEG us
    unsigned short* h1T = h0r + 3 * SEG;                   // 3*SEG us
    unsigned short* h1r = h1T + 3 * SEG;                   // 3*SEG us

    k_pre<<<NTOT, 64, 0, stream>>>(a, v, l, qmask, Wspk, out, xb, invn, cross);
    k_wt <<<dim3(16, 16, 3), 256, 0, stream>>>(W0, Wg, Wt);
    k_gram_mfma<<<dim3(N_DIA, 3), 256, 0, stream>>>(xb, invn, cross, blk, dinvp);

    const float th1 = 0.40546510810816438f;  // log(1.5)
    const float th2 = 0.22314355131420976f;  // log(1.25)

    // h0 = relu(x @ W0 + b0) -> h0T + h0row (bf16)
    k_gemm_mfma<<<dim3(4, 144), 256, 0, stream>>>(xb, Wt, b0, nullptr,
                                                  h0T, h0r, nullptr, 0.f, 0);
    // layer 1
    k_adjmul_mfma<<<dim3(2, N_DIA, 3), 256, 0, stream>>>(blk, cross, dinvp,
                                                         h0T, h0r, h0r, supb);
    k_gemm_mfma<<<dim3(4, 144), 256, 0, stream>>>(supb, Wt + (size_t)DD * DD, nullptr, supb,
                                                  h1T, h1r, nullptr, th1, 1);
    // layer 2
    k_adjmul_mfma<<<dim3(2, N_DIA, 3), 256, 0, stream>>>(blk, cross, dinvp,
                                                         h1T, h1r, h0r, supb);
    k_gemm_mfma<<<dim3(4, 144), 256, 0, stream>>>(supb, Wt + (size_t)2 * DD * DD, nullptr, supb,
                                                  nullptr, nullptr, out, th2, 2);
}